// Round 1
// baseline (1448.716 us; speedup 1.0000x reference)
//
#include <hip/hip_runtime.h>
#include <hip/hip_bf16.h>

// ---------------------------------------------------------------------------
// MPNN binding-affinity predictor, restructured:
//   per-edge GEMMs algebraically pushed to node side (W1 row-split, W2
//   post-aggregation), scatter-add replaced by CSR gather built per call.
// All fp32. ~50 GF of [10000,256]x[256,256] GEMMs + memory-bound edge pass.
// ---------------------------------------------------------------------------

#define HID 256

// ------------------------------ CSR build ----------------------------------

__global__ void hist_kernel(const int* __restrict__ dst, int* __restrict__ deg, int E) {
    int i = blockIdx.x * blockDim.x + threadIdx.x;
    if (i < E) atomicAdd(&deg[dst[i]], 1);
}

// single-block exclusive scan over n<=~16k elements; also emits float degrees
__global__ void scan_kernel(const int* __restrict__ deg, int* __restrict__ offs,
                            float* __restrict__ degf, int n) {
    __shared__ int buf[256];
    __shared__ int carry_s;
    int t = threadIdx.x;
    if (t == 0) carry_s = 0;
    __syncthreads();
    for (int base = 0; base < n; base += 256) {
        int v = (base + t < n) ? deg[base + t] : 0;
        buf[t] = v;
        __syncthreads();
        for (int off = 1; off < 256; off <<= 1) {
            int x = (t >= off) ? buf[t - off] : 0;
            __syncthreads();
            buf[t] += x;
            __syncthreads();
        }
        int incl = buf[t];
        int carry = carry_s;
        if (base + t < n) {
            offs[base + t] = carry + incl - v;
            degf[base + t] = (float)v;
        }
        __syncthreads();
        if (t == 255) carry_s = carry + buf[255];
        __syncthreads();
    }
    if (t == 0) offs[n] = carry_s;
}

__global__ void scatter_kernel(const int* __restrict__ src, const int* __restrict__ dst,
                               const int* __restrict__ offs, int* __restrict__ cursor,
                               int* __restrict__ csr_src, int* __restrict__ csr_eid, int E) {
    int i = blockIdx.x * blockDim.x + threadIdx.x;
    if (i < E) {
        int d = dst[i];
        int pos = atomicAdd(&cursor[d], 1);
        int idx = offs[d] + pos;
        csr_src[idx] = src[i];
        csr_eid[idx] = i;
    }
}

// ------------------------------ GEMM ---------------------------------------
// C[M,Nc] = act( A1[M,K1]@W1[K1,Nc] (+ A2[M,K2]@W2[K2,Nc]) + bias*rowscale )
// Tiled 64x64x16, 256 threads, 4x4 microtile per thread. fp32.

#define BM 64
#define BN 64
#define BK 16

__global__ __launch_bounds__(256) void gemm_kernel(
    const float* __restrict__ A1, const float* __restrict__ W1, int K1,
    const float* __restrict__ A2, const float* __restrict__ W2, int K2,
    const float* __restrict__ bias, const float* __restrict__ rowscale,
    float* __restrict__ C, int M, int Nc, int do_relu) {
    __shared__ float As[BK][BM + 4];
    __shared__ float Ws[BK][BN];

    const int tid = threadIdx.x;
    const int tx = tid & 15;
    const int ty = tid >> 4;
    const int rowBase = blockIdx.x * BM;
    const int colBase = blockIdx.y * BN;

    float acc[4][4] = {};

    for (int pass = 0; pass < 2; ++pass) {
        const float* A = pass ? A2 : A1;
        const float* W = pass ? W2 : W1;
        const int K = pass ? K2 : K1;
        if (K == 0) continue;
        const bool vec_ok = ((K & 3) == 0);
        for (int kb = 0; kb < K; kb += BK) {
            // A tile: thread t loads row m=t>>2, 4 ks at (t&3)*4; store transposed
            {
                int m = tid >> 2;
                int kq = (tid & 3) * 4;
                int row = rowBase + m;
                float4 v = make_float4(0.f, 0.f, 0.f, 0.f);
                if (row < M) {
                    int k0 = kb + kq;
                    if (vec_ok && k0 + 3 < K) {
                        v = *reinterpret_cast<const float4*>(A + (size_t)row * K + k0);
                    } else {
                        float tmp[4] = {0.f, 0.f, 0.f, 0.f};
#pragma unroll
                        for (int i = 0; i < 4; ++i)
                            if (k0 + i < K) tmp[i] = A[(size_t)row * K + k0 + i];
                        v = make_float4(tmp[0], tmp[1], tmp[2], tmp[3]);
                    }
                }
                As[kq + 0][m] = v.x;
                As[kq + 1][m] = v.y;
                As[kq + 2][m] = v.z;
                As[kq + 3][m] = v.w;
            }
            // W tile: thread t loads k=t>>4, 4 ns at (t&15)*4
            {
                int k = tid >> 4;
                int nq = (tid & 15) * 4;
                int kk = kb + k;
                float4 v = make_float4(0.f, 0.f, 0.f, 0.f);
                if (kk < K)
                    v = *reinterpret_cast<const float4*>(W + (size_t)kk * Nc + colBase + nq);
                *reinterpret_cast<float4*>(&Ws[k][nq]) = v;
            }
            __syncthreads();
#pragma unroll
            for (int k = 0; k < BK; ++k) {
                const float4 a = *reinterpret_cast<const float4*>(&As[k][ty * 4]);
                const float4 b = *reinterpret_cast<const float4*>(&Ws[k][tx * 4]);
                float av[4] = {a.x, a.y, a.z, a.w};
                float bv[4] = {b.x, b.y, b.z, b.w};
#pragma unroll
                for (int i = 0; i < 4; ++i)
#pragma unroll
                    for (int j = 0; j < 4; ++j) acc[i][j] = fmaf(av[i], bv[j], acc[i][j]);
            }
            __syncthreads();
        }
    }

    // epilogue
    float bv[4] = {0.f, 0.f, 0.f, 0.f};
    if (bias) {
#pragma unroll
        for (int j = 0; j < 4; ++j) bv[j] = bias[colBase + tx * 4 + j];
    }
#pragma unroll
    for (int i = 0; i < 4; ++i) {
        int row = rowBase + ty * 4 + i;
        if (row >= M) continue;
        float scale = rowscale ? rowscale[row] : 1.0f;
        float4 v;
        v.x = acc[i][0] + bv[0] * scale;
        v.y = acc[i][1] + bv[1] * scale;
        v.z = acc[i][2] + bv[2] * scale;
        v.w = acc[i][3] + bv[3] * scale;
        if (do_relu) {
            v.x = fmaxf(v.x, 0.f);
            v.y = fmaxf(v.y, 0.f);
            v.z = fmaxf(v.z, 0.f);
            v.w = fmaxf(v.w, 0.f);
        }
        *reinterpret_cast<float4*>(C + (size_t)row * Nc + colBase + tx * 4) = v;
    }
}

// --------------------------- edge aggregation ------------------------------
// Hagg[v] = sum over incoming edges e=(s,v): relu(P[s] + Q[v] + ef_e @ W1c)
// (b1 folded into Q). One wave per node, lane owns 4 consecutive channels.

__global__ __launch_bounds__(256) void aggregate_kernel(
    const float* __restrict__ P, const float* __restrict__ Q,
    const float* __restrict__ ef, const int* __restrict__ offs,
    const int* __restrict__ csr_src, const int* __restrict__ csr_eid,
    const float* __restrict__ W1c, float* __restrict__ Hagg, int n) {
    const int wave = threadIdx.x >> 6;
    const int lane = threadIdx.x & 63;
    const int node = blockIdx.x * 4 + wave;
    if (node >= n) return;
    const int col = lane * 4;

    float4 wc[6];
#pragma unroll
    for (int k = 0; k < 6; ++k) wc[k] = *reinterpret_cast<const float4*>(W1c + k * HID + col);
    const float4 q = *reinterpret_cast<const float4*>(Q + (size_t)node * HID + col);
    float4 acc = make_float4(0.f, 0.f, 0.f, 0.f);

    const int beg = offs[node];
    const int end = offs[node + 1];
#pragma unroll 2
    for (int j = beg; j < end; ++j) {
        int s = csr_src[j];
        int e = csr_eid[j];
        const float4 p = *reinterpret_cast<const float4*>(P + (size_t)s * HID + col);
        const float* efp = ef + (size_t)e * 6;
        float e0 = efp[0], e1 = efp[1], e2 = efp[2], e3 = efp[3], e4 = efp[4], e5 = efp[5];
        float4 h;
        h.x = p.x + q.x + e0 * wc[0].x + e1 * wc[1].x + e2 * wc[2].x + e3 * wc[3].x + e4 * wc[4].x + e5 * wc[5].x;
        h.y = p.y + q.y + e0 * wc[0].y + e1 * wc[1].y + e2 * wc[2].y + e3 * wc[3].y + e4 * wc[4].y + e5 * wc[5].y;
        h.z = p.z + q.z + e0 * wc[0].z + e1 * wc[1].z + e2 * wc[2].z + e3 * wc[3].z + e4 * wc[4].z + e5 * wc[5].z;
        h.w = p.w + q.w + e0 * wc[0].w + e1 * wc[1].w + e2 * wc[2].w + e3 * wc[3].w + e4 * wc[4].w + e5 * wc[5].w;
        acc.x += fmaxf(h.x, 0.f);
        acc.y += fmaxf(h.y, 0.f);
        acc.z += fmaxf(h.z, 0.f);
        acc.w += fmaxf(h.w, 0.f);
    }
    *reinterpret_cast<float4*>(Hagg + (size_t)node * HID + col) = acc;
}

// ------------------------------- readout -----------------------------------

__global__ __launch_bounds__(256) void readout_dot_kernel(
    const float* __restrict__ h2, const float* __restrict__ w3,
    float* __restrict__ accum, int n) {
    const int wave = threadIdx.x >> 6;
    const int lane = threadIdx.x & 63;
    const int nwaves = gridDim.x * 4;
    const int wid = blockIdx.x * 4 + wave;
    const float2 w = *reinterpret_cast<const float2*>(w3 + lane * 2);
    float local = 0.f;
    for (int node = wid; node < n; node += nwaves) {
        const float2 v = *reinterpret_cast<const float2*>(h2 + (size_t)node * 128 + lane * 2);
        local = fmaf(v.x, w.x, local);
        local = fmaf(v.y, w.y, local);
    }
    for (int off = 32; off > 0; off >>= 1) local += __shfl_down(local, off, 64);
    if (lane == 0) atomicAdd(accum, local);
}

__global__ void finalize_kernel(const float* __restrict__ accum, const float* __restrict__ b3,
                                float* __restrict__ out, float inv_n) {
    out[0] = accum[0] * inv_n + b3[0];
}

// ------------------------------- driver ------------------------------------

extern "C" void kernel_launch(void* const* d_in, const int* in_sizes, int n_in,
                              void* d_out, int out_size, void* d_ws, size_t ws_size,
                              hipStream_t stream) {
    const float* atom   = (const float*)d_in[0];   // [N,62]
    const int*   eidx   = (const int*)d_in[1];     // [2,E]
    const float* ef     = (const float*)d_in[2];   // [E,6]
    const float* emb_w  = (const float*)d_in[3];   // [62,256]
    const float* emb_b  = (const float*)d_in[4];   // [256]
    const float* msg_w1 = (const float*)d_in[5];   // [L,518,256]
    const float* msg_b1 = (const float*)d_in[6];   // [L,256]
    const float* msg_w2 = (const float*)d_in[7];   // [L,256,256]
    const float* msg_b2 = (const float*)d_in[8];   // [L,256]
    const float* upd_w1 = (const float*)d_in[9];   // [L,512,256]
    const float* upd_b1 = (const float*)d_in[10];  // [L,256]
    const float* upd_w2 = (const float*)d_in[11];  // [L,256,256]
    const float* upd_b2 = (const float*)d_in[12];  // [L,256]
    const float* r_w1   = (const float*)d_in[13];  // [256,256]
    const float* r_b1   = (const float*)d_in[14];
    const float* r_w2   = (const float*)d_in[15];  // [256,128]
    const float* r_b2   = (const float*)d_in[16];
    const float* r_w3   = (const float*)d_in[17];  // [128,1]
    const float* r_b3   = (const float*)d_in[18];

    const int N = in_sizes[0] / 62;
    const int E = in_sizes[1] / 2;
    const int L = in_sizes[5] / (518 * 256);
    const int* src = eidx;
    const int* dst = eidx + E;

    // workspace bump allocator (256B aligned)
    char* wp = (char*)d_ws;
    auto alloc = [&](size_t bytes) -> void* {
        void* p = (void*)wp;
        wp += (bytes + 255) & ~(size_t)255;
        return p;
    };
    int*   deg     = (int*)alloc((size_t)N * 4);
    int*   cursor  = (int*)alloc((size_t)N * 4);
    float* accum   = (float*)alloc(256);
    size_t zero_bytes = (size_t)((char*)accum - (char*)d_ws) + 256;
    float* degf    = (float*)alloc((size_t)N * 4);
    int*   offs    = (int*)alloc((size_t)(N + 1) * 4);
    int*   csr_src = (int*)alloc((size_t)E * 4);
    int*   csr_eid = (int*)alloc((size_t)E * 4);
    float* x       = (float*)alloc((size_t)N * HID * 4);
    float* P       = (float*)alloc((size_t)N * HID * 4);
    float* Q       = (float*)alloc((size_t)N * HID * 4);
    float* Hagg    = (float*)alloc((size_t)N * HID * 4);

    hipMemsetAsync(d_ws, 0, zero_bytes, stream);

    // CSR build (by dst)
    hist_kernel<<<(E + 255) / 256, 256, 0, stream>>>(dst, deg, E);
    scan_kernel<<<1, 256, 0, stream>>>(deg, offs, degf, N);
    scatter_kernel<<<(E + 255) / 256, 256, 0, stream>>>(src, dst, offs, cursor,
                                                        csr_src, csr_eid, E);

    const int mblk = (N + BM - 1) / BM;
    dim3 g256(mblk, HID / BN);
    dim3 g128(mblk, 128 / BN);
    dim3 blk(256);

    // embed: x = atom @ emb_w + emb_b
    gemm_kernel<<<g256, blk, 0, stream>>>(atom, emb_w, 62, nullptr, nullptr, 0,
                                          emb_b, nullptr, x, N, HID, 0);

    for (int l = 0; l < L; ++l) {
        const float* w1  = msg_w1 + (size_t)l * 518 * HID;
        const float* b1  = msg_b1 + (size_t)l * HID;
        const float* w2  = msg_w2 + (size_t)l * HID * HID;
        const float* b2  = msg_b2 + (size_t)l * HID;
        const float* u1  = upd_w1 + (size_t)l * 512 * HID;
        const float* ub1 = upd_b1 + (size_t)l * HID;
        const float* u2  = upd_w2 + (size_t)l * HID * HID;
        const float* ub2 = upd_b2 + (size_t)l * HID;

        // P = x @ W1[0:256]          (src part)
        gemm_kernel<<<g256, blk, 0, stream>>>(x, w1, HID, nullptr, nullptr, 0,
                                              nullptr, nullptr, P, N, HID, 0);
        // Q = x @ W1[256:512] + b1   (dst part, bias folded)
        gemm_kernel<<<g256, blk, 0, stream>>>(x, w1 + 256 * HID, HID, nullptr, nullptr, 0,
                                              b1, nullptr, Q, N, HID, 0);
        // Hagg[v] = sum_e relu(P[src]+Q[v]+ef@W1c)
        aggregate_kernel<<<(N + 3) / 4, blk, 0, stream>>>(P, Q, ef, offs, csr_src, csr_eid,
                                                          w1 + 512 * HID, Hagg, N);
        // agg = Hagg @ W2 + deg*b2   (into P; P is dead now)
        gemm_kernel<<<g256, blk, 0, stream>>>(Hagg, w2, HID, nullptr, nullptr, 0,
                                              b2, degf, P, N, HID, 0);
        // u = relu(x @ U1a + agg @ U1b + ub1)  (into Q)
        gemm_kernel<<<g256, blk, 0, stream>>>(x, u1, HID, P, u1 + 256 * HID, HID,
                                              ub1, nullptr, Q, N, HID, 1);
        // x = u @ U2 + ub2
        gemm_kernel<<<g256, blk, 0, stream>>>(Q, u2, HID, nullptr, nullptr, 0,
                                              ub2, nullptr, x, N, HID, 0);
    }

    // readout
    gemm_kernel<<<g256, blk, 0, stream>>>(x, r_w1, HID, nullptr, nullptr, 0,
                                          r_b1, nullptr, P, N, HID, 1);
    gemm_kernel<<<g128, blk, 0, stream>>>(P, r_w2, HID, nullptr, nullptr, 0,
                                          r_b2, nullptr, Q, N, 128, 1);
    readout_dot_kernel<<<256, blk, 0, stream>>>(Q, r_w3, accum, N);
    finalize_kernel<<<1, 1, 0, stream>>>(accum, r_b3, (float*)d_out, 1.0f / (float)N);
}

// Round 2
// 837.591 us; speedup vs baseline: 1.7296x; 1.7296x over previous
//
#include <hip/hip_runtime.h>
#include <hip/hip_bf16.h>

// ---------------------------------------------------------------------------
// MPNN binding-affinity predictor.
// R2: node GEMMs moved to matrix cores via split-bf16 (hi/lo) 3-MFMA fp32
// emulation; weights pre-transposed/converted once per call; P,Q fused into
// one Nc=512 GEMM (b1 folded into aggregate).
// ---------------------------------------------------------------------------

#define HID 256

typedef short short8 __attribute__((ext_vector_type(8)));
typedef float f32x4 __attribute__((ext_vector_type(4)));

__device__ __forceinline__ unsigned short bf_rne(float f) {
    unsigned u = __float_as_uint(f);
    u += 0x7fffu + ((u >> 16) & 1u);
    return (unsigned short)(u >> 16);
}

__device__ __forceinline__ void split_pack8(const float* f, int4& hp, int4& lp) {
    unsigned short h[8], l[8];
#pragma unroll
    for (int j = 0; j < 8; ++j) {
        unsigned short hh = bf_rne(f[j]);
        float fh = __uint_as_float((unsigned)hh << 16);
        h[j] = hh;
        l[j] = bf_rne(f[j] - fh);
    }
    hp.x = (int)(h[0] | ((unsigned)h[1] << 16));
    hp.y = (int)(h[2] | ((unsigned)h[3] << 16));
    hp.z = (int)(h[4] | ((unsigned)h[5] << 16));
    hp.w = (int)(h[6] | ((unsigned)h[7] << 16));
    lp.x = (int)(l[0] | ((unsigned)l[1] << 16));
    lp.y = (int)(l[2] | ((unsigned)l[3] << 16));
    lp.z = (int)(l[4] | ((unsigned)l[5] << 16));
    lp.w = (int)(l[6] | ((unsigned)l[7] << 16));
}

// ------------------------------ CSR build ----------------------------------

__global__ void hist_kernel(const int* __restrict__ dst, int* __restrict__ deg, int E) {
    int i = blockIdx.x * blockDim.x + threadIdx.x;
    if (i < E) atomicAdd(&deg[dst[i]], 1);
}

__global__ void scan_kernel(const int* __restrict__ deg, int* __restrict__ offs,
                            float* __restrict__ degf, int n) {
    __shared__ int buf[256];
    __shared__ int carry_s;
    int t = threadIdx.x;
    if (t == 0) carry_s = 0;
    __syncthreads();
    for (int base = 0; base < n; base += 256) {
        int v = (base + t < n) ? deg[base + t] : 0;
        buf[t] = v;
        __syncthreads();
        for (int off = 1; off < 256; off <<= 1) {
            int x = (t >= off) ? buf[t - off] : 0;
            __syncthreads();
            buf[t] += x;
            __syncthreads();
        }
        int incl = buf[t];
        int carry = carry_s;
        if (base + t < n) {
            offs[base + t] = carry + incl - v;
            degf[base + t] = (float)v;
        }
        __syncthreads();
        if (t == 255) carry_s = carry + buf[255];
        __syncthreads();
    }
    if (t == 0) offs[n] = carry_s;
}

__global__ void scatter_kernel(const int* __restrict__ src, const int* __restrict__ dst,
                               const int* __restrict__ offs, int* __restrict__ cursor,
                               int* __restrict__ csr_src, int* __restrict__ csr_eid, int E) {
    int i = blockIdx.x * blockDim.x + threadIdx.x;
    if (i < E) {
        int d = dst[i];
        int pos = atomicAdd(&cursor[d], 1);
        int idx = offs[d] + pos;
        csr_src[idx] = src[i];
        csr_eid[idx] = i;
    }
}

// ------------------------ weight convert (one launch) ----------------------
// src [Kreal, srcN] fp32 row-major -> dh/dl [srcN][Kpad] bf16 (transposed,
// zero-padded to Kpad). Block = 64 n x 32 k.

struct CDesc {
    const float* src;
    unsigned short* dh;
    unsigned short* dl;
    int Kreal, Kpad, srcN, tile0;
};
struct CTab {
    CDesc d[40];
    int nd;
};

__global__ __launch_bounds__(256) void convert_weights(CTab tab) {
    const int bid = blockIdx.x;
    int idx = 0;
    for (int i = 1; i < tab.nd; ++i)
        if (tab.d[i].tile0 <= bid) idx = i;
    const CDesc d = tab.d[idx];
    const int q = bid - d.tile0;
    const int ntN = d.srcN >> 6;
    const int kb = (q / ntN) * 32;
    const int nb = (q % ntN) * 64;
    const int n = nb + (threadIdx.x & 63);
    const int k0 = kb + (threadIdx.x >> 6) * 8;
    float f[8];
#pragma unroll
    for (int j = 0; j < 8; ++j) {
        int k = k0 + j;
        f[j] = (k < d.Kreal) ? d.src[(size_t)k * d.srcN + n] : 0.f;
    }
    int4 hp, lp;
    split_pack8(f, hp, lp);
    *reinterpret_cast<int4*>(&d.dh[(size_t)n * d.Kpad + k0]) = hp;
    *reinterpret_cast<int4*>(&d.dl[(size_t)n * d.Kpad + k0]) = lp;
}

// ------------------------------ MFMA GEMM ----------------------------------
// C[M,Nc] = act( A1@W1 (+ A2@W2) + bias*rowscale ), A fp32 split to bf16
// hi/lo in LDS, W pre-converted [Nc][K] bf16 hi/lo. 64x64 tile, BK=32,
// 4 waves (2x2), each wave 2x2 16x16x32 MFMA tiles, 12 MFMA/k-iter.

#define ASTR 40  // LDS row stride in bf16 elems (64B+16B pad: conflict-free)

__global__ __launch_bounds__(256) void mfma_gemm(
    const float* __restrict__ A1, int lda1, const unsigned short* __restrict__ W1h,
    const unsigned short* __restrict__ W1l, int K1,
    const float* __restrict__ A2, int lda2, const unsigned short* __restrict__ W2h,
    const unsigned short* __restrict__ W2l, int K2,
    const float* __restrict__ bias, const float* __restrict__ rowscale,
    float* __restrict__ C, int M, int Nc, int do_relu) {
    __shared__ __align__(16) unsigned short Ah[64 * ASTR];
    __shared__ __align__(16) unsigned short Al[64 * ASTR];
    __shared__ __align__(16) unsigned short Bh[64 * ASTR];
    __shared__ __align__(16) unsigned short Bl[64 * ASTR];

    const int tid = threadIdx.x;
    const int lane = tid & 63;
    const int wave = tid >> 6;
    const int waveM = (wave >> 1) * 32;
    const int waveN = (wave & 1) * 32;
    const int m0 = lane & 15;
    const int quad = lane >> 4;
    const int rowBase = blockIdx.x * 64;
    const int colBase = blockIdx.y * 64;
    const int sr = tid >> 2;   // staging row (A) / n-row (B): 0..63
    const int sseg = tid & 3;  // k-segment of 8
    const int arow = rowBase + sr;

    const f32x4 z = {0.f, 0.f, 0.f, 0.f};
    f32x4 acc[2][2] = {{z, z}, {z, z}};

    for (int pass = 0; pass < 2; ++pass) {
        const float* A = pass ? A2 : A1;
        if (!A) continue;
        const int lda = pass ? lda2 : lda1;
        const unsigned short* Wh = pass ? W2h : W1h;
        const unsigned short* Wl = pass ? W2l : W1l;
        const int K = pass ? K2 : K1;
        const bool vec = ((lda & 3) == 0);

        for (int kb = 0; kb < K; kb += 32) {
            // stage A (fp32 -> hi/lo bf16)
            {
                float f[8];
                if (arow < M) {
                    const float* Ap = A + (size_t)arow * lda + kb + sseg * 8;
                    if (vec) {
                        float4 u0 = *reinterpret_cast<const float4*>(Ap);
                        float4 u1 = *reinterpret_cast<const float4*>(Ap + 4);
                        f[0] = u0.x; f[1] = u0.y; f[2] = u0.z; f[3] = u0.w;
                        f[4] = u1.x; f[5] = u1.y; f[6] = u1.z; f[7] = u1.w;
                    } else {
#pragma unroll
                        for (int j = 0; j < 8; ++j) {
                            int k = kb + sseg * 8 + j;
                            f[j] = (k < lda) ? Ap[j] : 0.f;
                        }
                    }
                } else {
#pragma unroll
                    for (int j = 0; j < 8; ++j) f[j] = 0.f;
                }
                int4 hp, lp;
                split_pack8(f, hp, lp);
                *reinterpret_cast<int4*>(&Ah[sr * ASTR + sseg * 8]) = hp;
                *reinterpret_cast<int4*>(&Al[sr * ASTR + sseg * 8]) = lp;
            }
            // stage B (pre-converted [Nc][K] bf16, straight b128 copies)
            {
                size_t off = (size_t)(colBase + sr) * K + kb + sseg * 8;
                *reinterpret_cast<int4*>(&Bh[sr * ASTR + sseg * 8]) =
                    *reinterpret_cast<const int4*>(&Wh[off]);
                *reinterpret_cast<int4*>(&Bl[sr * ASTR + sseg * 8]) =
                    *reinterpret_cast<const int4*>(&Wl[off]);
            }
            __syncthreads();

            const short8 a0h = *reinterpret_cast<const short8*>(&Ah[(waveM + m0) * ASTR + quad * 8]);
            const short8 a1h = *reinterpret_cast<const short8*>(&Ah[(waveM + 16 + m0) * ASTR + quad * 8]);
            const short8 a0l = *reinterpret_cast<const short8*>(&Al[(waveM + m0) * ASTR + quad * 8]);
            const short8 a1l = *reinterpret_cast<const short8*>(&Al[(waveM + 16 + m0) * ASTR + quad * 8]);
            const short8 b0h = *reinterpret_cast<const short8*>(&Bh[(waveN + m0) * ASTR + quad * 8]);
            const short8 b1h = *reinterpret_cast<const short8*>(&Bh[(waveN + 16 + m0) * ASTR + quad * 8]);
            const short8 b0l = *reinterpret_cast<const short8*>(&Bl[(waveN + m0) * ASTR + quad * 8]);
            const short8 b1l = *reinterpret_cast<const short8*>(&Bl[(waveN + 16 + m0) * ASTR + quad * 8]);

            acc[0][0] = __builtin_amdgcn_mfma_f32_16x16x32_bf16(a0h, b0h, acc[0][0], 0, 0, 0);
            acc[0][1] = __builtin_amdgcn_mfma_f32_16x16x32_bf16(a0h, b1h, acc[0][1], 0, 0, 0);
            acc[1][0] = __builtin_amdgcn_mfma_f32_16x16x32_bf16(a1h, b0h, acc[1][0], 0, 0, 0);
            acc[1][1] = __builtin_amdgcn_mfma_f32_16x16x32_bf16(a1h, b1h, acc[1][1], 0, 0, 0);
            acc[0][0] = __builtin_amdgcn_mfma_f32_16x16x32_bf16(a0l, b0h, acc[0][0], 0, 0, 0);
            acc[0][1] = __builtin_amdgcn_mfma_f32_16x16x32_bf16(a0l, b1h, acc[0][1], 0, 0, 0);
            acc[1][0] = __builtin_amdgcn_mfma_f32_16x16x32_bf16(a1l, b0h, acc[1][0], 0, 0, 0);
            acc[1][1] = __builtin_amdgcn_mfma_f32_16x16x32_bf16(a1l, b1h, acc[1][1], 0, 0, 0);
            acc[0][0] = __builtin_amdgcn_mfma_f32_16x16x32_bf16(a0h, b0l, acc[0][0], 0, 0, 0);
            acc[0][1] = __builtin_amdgcn_mfma_f32_16x16x32_bf16(a0h, b1l, acc[0][1], 0, 0, 0);
            acc[1][0] = __builtin_amdgcn_mfma_f32_16x16x32_bf16(a1h, b0l, acc[1][0], 0, 0, 0);
            acc[1][1] = __builtin_amdgcn_mfma_f32_16x16x32_bf16(a1h, b1l, acc[1][1], 0, 0, 0);

            __syncthreads();
        }
    }

    // epilogue: C[row=quad*4+reg][col=lane&15] per 16x16 tile
    float bv[2] = {0.f, 0.f};
    int col[2];
#pragma unroll
    for (int tn = 0; tn < 2; ++tn) {
        col[tn] = colBase + waveN + tn * 16 + m0;
        if (bias) bv[tn] = bias[col[tn]];
    }
#pragma unroll
    for (int tm = 0; tm < 2; ++tm) {
#pragma unroll
        for (int reg = 0; reg < 4; ++reg) {
            int row = rowBase + waveM + tm * 16 + quad * 4 + reg;
            if (row >= M) continue;
            float rs = rowscale ? rowscale[row] : 1.0f;
#pragma unroll
            for (int tn = 0; tn < 2; ++tn) {
                float v = acc[tm][tn][reg] + bv[tn] * rs;
                if (do_relu) v = fmaxf(v, 0.f);
                C[(size_t)row * Nc + col[tn]] = v;
            }
        }
    }
}

// --------------------------- edge aggregation ------------------------------
// Hagg[v] = sum over incoming edges e=(s,v): relu(P[s] + Q[v] + b1 + ef_e@W1c)
// P = PQ[:,0:256], Q = PQ[:,256:512] (row stride 512). One wave per node.

__global__ __launch_bounds__(256) void aggregate_kernel(
    const float* __restrict__ PQ, const float* __restrict__ b1,
    const float* __restrict__ ef, const int* __restrict__ offs,
    const int* __restrict__ csr_src, const int* __restrict__ csr_eid,
    const float* __restrict__ W1c, float* __restrict__ Hagg, int n) {
    const int wave = threadIdx.x >> 6;
    const int lane = threadIdx.x & 63;
    const int node = blockIdx.x * 4 + wave;
    if (node >= n) return;
    const int col = lane * 4;

    float4 wc[6];
#pragma unroll
    for (int k = 0; k < 6; ++k) wc[k] = *reinterpret_cast<const float4*>(W1c + k * HID + col);
    float4 q = *reinterpret_cast<const float4*>(PQ + (size_t)node * 512 + 256 + col);
    const float4 bb = *reinterpret_cast<const float4*>(b1 + col);
    q.x += bb.x; q.y += bb.y; q.z += bb.z; q.w += bb.w;
    float4 acc = make_float4(0.f, 0.f, 0.f, 0.f);

    const int beg = offs[node];
    const int end = offs[node + 1];
#pragma unroll 2
    for (int j = beg; j < end; ++j) {
        int s = csr_src[j];
        int e = csr_eid[j];
        const float4 p = *reinterpret_cast<const float4*>(PQ + (size_t)s * 512 + col);
        const float* efp = ef + (size_t)e * 6;
        float e0 = efp[0], e1 = efp[1], e2 = efp[2], e3 = efp[3], e4 = efp[4], e5 = efp[5];
        float4 h;
        h.x = p.x + q.x + e0 * wc[0].x + e1 * wc[1].x + e2 * wc[2].x + e3 * wc[3].x + e4 * wc[4].x + e5 * wc[5].x;
        h.y = p.y + q.y + e0 * wc[0].y + e1 * wc[1].y + e2 * wc[2].y + e3 * wc[3].y + e4 * wc[4].y + e5 * wc[5].y;
        h.z = p.z + q.z + e0 * wc[0].z + e1 * wc[1].z + e2 * wc[2].z + e3 * wc[3].z + e4 * wc[4].z + e5 * wc[5].z;
        h.w = p.w + q.w + e0 * wc[0].w + e1 * wc[1].w + e2 * wc[2].w + e3 * wc[3].w + e4 * wc[4].w + e5 * wc[5].w;
        acc.x += fmaxf(h.x, 0.f);
        acc.y += fmaxf(h.y, 0.f);
        acc.z += fmaxf(h.z, 0.f);
        acc.w += fmaxf(h.w, 0.f);
    }
    *reinterpret_cast<float4*>(Hagg + (size_t)node * HID + col) = acc;
}

// ------------------------------- readout -----------------------------------

__global__ __launch_bounds__(256) void readout_dot_kernel(
    const float* __restrict__ h2, const float* __restrict__ w3,
    float* __restrict__ accum, int n) {
    const int wave = threadIdx.x >> 6;
    const int lane = threadIdx.x & 63;
    const int nwaves = gridDim.x * 4;
    const int wid = blockIdx.x * 4 + wave;
    const float2 w = *reinterpret_cast<const float2*>(w3 + lane * 2);
    float local = 0.f;
    for (int node = wid; node < n; node += nwaves) {
        const float2 v = *reinterpret_cast<const float2*>(h2 + (size_t)node * 128 + lane * 2);
        local = fmaf(v.x, w.x, local);
        local = fmaf(v.y, w.y, local);
    }
    for (int off = 32; off > 0; off >>= 1) local += __shfl_down(local, off, 64);
    if (lane == 0) atomicAdd(accum, local);
}

__global__ void finalize_kernel(const float* __restrict__ accum, const float* __restrict__ b3,
                                float* __restrict__ out, float inv_n) {
    out[0] = accum[0] * inv_n + b3[0];
}

// ------------------------------- driver ------------------------------------

extern "C" void kernel_launch(void* const* d_in, const int* in_sizes, int n_in,
                              void* d_out, int out_size, void* d_ws, size_t ws_size,
                              hipStream_t stream) {
    const float* atom   = (const float*)d_in[0];   // [N,62]
    const int*   eidx   = (const int*)d_in[1];     // [2,E]
    const float* ef     = (const float*)d_in[2];   // [E,6]
    const float* emb_w  = (const float*)d_in[3];   // [62,256]
    const float* emb_b  = (const float*)d_in[4];   // [256]
    const float* msg_w1 = (const float*)d_in[5];   // [L,518,256]
    const float* msg_b1 = (const float*)d_in[6];   // [L,256]
    const float* msg_w2 = (const float*)d_in[7];   // [L,256,256]
    const float* msg_b2 = (const float*)d_in[8];   // [L,256]
    const float* upd_w1 = (const float*)d_in[9];   // [L,512,256]
    const float* upd_b1 = (const float*)d_in[10];  // [L,256]
    const float* upd_w2 = (const float*)d_in[11];  // [L,256,256]
    const float* upd_b2 = (const float*)d_in[12];  // [L,256]
    const float* r_w1   = (const float*)d_in[13];  // [256,256]
    const float* r_b1   = (const float*)d_in[14];
    const float* r_w2   = (const float*)d_in[15];  // [256,128]
    const float* r_b2   = (const float*)d_in[16];
    const float* r_w3   = (const float*)d_in[17];  // [128,1]
    const float* r_b3   = (const float*)d_in[18];

    const int N = in_sizes[0] / 62;
    const int E = in_sizes[1] / 2;
    const int L = in_sizes[5] / (518 * 256);
    const int* src = eidx;
    const int* dst = eidx + E;

    // workspace bump allocator (256B aligned)
    char* wp = (char*)d_ws;
    auto alloc = [&](size_t bytes) -> void* {
        void* p = (void*)wp;
        wp += (bytes + 255) & ~(size_t)255;
        return p;
    };
    int*   deg     = (int*)alloc((size_t)N * 4);
    int*   cursor  = (int*)alloc((size_t)N * 4);
    float* accum   = (float*)alloc(256);
    size_t zero_bytes = (size_t)((char*)accum - (char*)d_ws) + 256;
    float* degf    = (float*)alloc((size_t)N * 4);
    int*   offs    = (int*)alloc((size_t)(N + 1) * 4);
    int*   csr_src = (int*)alloc((size_t)E * 4);
    int*   csr_eid = (int*)alloc((size_t)E * 4);

    // converted weights (bf16 hi/lo planes, transposed [Nc][Kpad])
    const int EMB_P = 256 * 64, PQ_P = 512 * 256, SQ_P = 256 * 256, R2_P = 128 * 256;
    unsigned short* w_emb = (unsigned short*)alloc((size_t)EMB_P * 2 * 2);
    unsigned short *w_pq[6], *w_w2[6], *w_u1a[6], *w_u1b[6], *w_u2[6];
    for (int l = 0; l < L; ++l) {
        w_pq[l]  = (unsigned short*)alloc((size_t)PQ_P * 2 * 2);
        w_w2[l]  = (unsigned short*)alloc((size_t)SQ_P * 2 * 2);
        w_u1a[l] = (unsigned short*)alloc((size_t)SQ_P * 2 * 2);
        w_u1b[l] = (unsigned short*)alloc((size_t)SQ_P * 2 * 2);
        w_u2[l]  = (unsigned short*)alloc((size_t)SQ_P * 2 * 2);
    }
    unsigned short* w_r1 = (unsigned short*)alloc((size_t)SQ_P * 2 * 2);
    unsigned short* w_r2 = (unsigned short*)alloc((size_t)R2_P * 2 * 2);

    float* x    = (float*)alloc((size_t)N * HID * 4);
    float* PQ   = (float*)alloc((size_t)N * 512 * 4);   // also AGG / r1-out space
    float* Hagg = (float*)alloc((size_t)N * HID * 4);   // also upd1-out / r2-out

    hipMemsetAsync(d_ws, 0, zero_bytes, stream);

    // CSR build (by dst)
    hist_kernel<<<(E + 255) / 256, 256, 0, stream>>>(dst, deg, E);
    scan_kernel<<<1, 256, 0, stream>>>(deg, offs, degf, N);
    scatter_kernel<<<(E + 255) / 256, 256, 0, stream>>>(src, dst, offs, cursor,
                                                        csr_src, csr_eid, E);

    // weight conversion: one launch, descriptor table in kernarg
    CTab tab;
    int nd = 0, tiles = 0;
    auto addDesc = [&](const float* s, unsigned short* dh, unsigned short* dl,
                       int Kreal, int Kpad, int srcN) {
        tab.d[nd] = {s, dh, dl, Kreal, Kpad, srcN, tiles};
        tiles += (Kpad / 32) * (srcN / 64);
        ++nd;
    };
    addDesc(emb_w, w_emb, w_emb + EMB_P, 62, 64, 256);
    for (int l = 0; l < L; ++l) {
        const float* m1 = msg_w1 + (size_t)l * 518 * 256;
        addDesc(m1,              w_pq[l],         w_pq[l] + PQ_P,         256, 256, 256);
        addDesc(m1 + 256 * 256,  w_pq[l] + SQ_P,  w_pq[l] + PQ_P + SQ_P,  256, 256, 256);
        addDesc(msg_w2 + (size_t)l * SQ_P, w_w2[l], w_w2[l] + SQ_P, 256, 256, 256);
        const float* u1 = upd_w1 + (size_t)l * 512 * 256;
        addDesc(u1,             w_u1a[l], w_u1a[l] + SQ_P, 256, 256, 256);
        addDesc(u1 + 256 * 256, w_u1b[l], w_u1b[l] + SQ_P, 256, 256, 256);
        addDesc(upd_w2 + (size_t)l * SQ_P, w_u2[l], w_u2[l] + SQ_P, 256, 256, 256);
    }
    addDesc(r_w1, w_r1, w_r1 + SQ_P, 256, 256, 256);
    addDesc(r_w2, w_r2, w_r2 + R2_P, 256, 256, 128);
    tab.nd = nd;
    convert_weights<<<tiles, 256, 0, stream>>>(tab);

    const int mblk = (N + 63) / 64;
    dim3 blk(256);

    // embed: x = atom @ emb_w + emb_b  (K=62 padded to 64)
    mfma_gemm<<<dim3(mblk, 4), blk, 0, stream>>>(
        atom, 62, w_emb, w_emb + EMB_P, 64,
        nullptr, 0, nullptr, nullptr, 0,
        emb_b, nullptr, x, N, HID, 0);

    for (int l = 0; l < L; ++l) {
        const float* b1  = msg_b1 + (size_t)l * HID;
        const float* b2  = msg_b2 + (size_t)l * HID;
        const float* ub1 = upd_b1 + (size_t)l * HID;
        const float* ub2 = upd_b2 + (size_t)l * HID;
        const float* w1c = msg_w1 + (size_t)l * 518 * 256 + 512 * 256;

        // PQ = x @ [W1a | W1b]  (Nc=512, b1 folded into aggregate)
        mfma_gemm<<<dim3(mblk, 8), blk, 0, stream>>>(
            x, HID, w_pq[l], w_pq[l] + PQ_P, HID,
            nullptr, 0, nullptr, nullptr, 0,
            nullptr, nullptr, PQ, N, 512, 0);
        // Hagg[v] = sum_e relu(P[src]+Q[v]+b1+ef@W1c)
        aggregate_kernel<<<(N + 3) / 4, blk, 0, stream>>>(PQ, b1, ef, offs, csr_src,
                                                          csr_eid, w1c, Hagg, N);
        // AGG = Hagg @ W2 + deg*b2   (into PQ space)
        mfma_gemm<<<dim3(mblk, 4), blk, 0, stream>>>(
            Hagg, HID, w_w2[l], w_w2[l] + SQ_P, HID,
            nullptr, 0, nullptr, nullptr, 0,
            b2, degf, PQ, N, HID, 0);
        // U = relu(x@U1a + AGG@U1b + ub1)  (into Hagg space)
        mfma_gemm<<<dim3(mblk, 4), blk, 0, stream>>>(
            x, HID, w_u1a[l], w_u1a[l] + SQ_P, HID,
            PQ, HID, w_u1b[l], w_u1b[l] + SQ_P, HID,
            ub1, nullptr, Hagg, N, HID, 1);
        // x = U @ U2 + ub2
        mfma_gemm<<<dim3(mblk, 4), blk, 0, stream>>>(
            Hagg, HID, w_u2[l], w_u2[l] + SQ_P, HID,
            nullptr, 0, nullptr, nullptr, 0,
            ub2, nullptr, x, N, HID, 0);
    }

    // readout
    mfma_gemm<<<dim3(mblk, 4), blk, 0, stream>>>(
        x, HID, w_r1, w_r1 + SQ_P, HID,
        nullptr, 0, nullptr, nullptr, 0,
        r_b1, nullptr, PQ, N, HID, 1);
    mfma_gemm<<<dim3(mblk, 2), blk, 0, stream>>>(
        PQ, HID, w_r2, w_r2 + R2_P, HID,
        nullptr, 0, nullptr, nullptr, 0,
        r_b2, nullptr, Hagg, N, 128, 1);
    readout_dot_kernel<<<256, blk, 0, stream>>>(Hagg, r_w3, accum, N);
    finalize_kernel<<<1, 1, 0, stream>>>(accum, r_b3, (float*)d_out, 1.0f / (float)N);
}

// Round 3
// 653.464 us; speedup vs baseline: 2.2170x; 1.2818x over previous
//
#include <hip/hip_runtime.h>
#include <hip/hip_bf16.h>
#include <hip/hip_fp16.h>

// ---------------------------------------------------------------------------
// MPNN binding-affinity predictor. R3:
//  - scan rewritten (shuffle-based)              : 45.7 us -> ~4 us
//  - U2/W2 folded into neighbor-layer weights    : 5 -> 3 dispatches/layer
//  - PQ stored fp16 (gather bytes halved), ef permuted into CSR order
// GEMMs: split-bf16 (hi/lo) 3-MFMA fp32 emulation on matrix cores.
// ---------------------------------------------------------------------------

#define HID 256

typedef short short8 __attribute__((ext_vector_type(8)));
typedef float f32x4 __attribute__((ext_vector_type(4)));

__device__ __forceinline__ unsigned short bf_rne(float f) {
    unsigned u = __float_as_uint(f);
    u += 0x7fffu + ((u >> 16) & 1u);
    return (unsigned short)(u >> 16);
}

__device__ __forceinline__ void split_pack8(const float* f, int4& hp, int4& lp) {
    unsigned short h[8], l[8];
#pragma unroll
    for (int j = 0; j < 8; ++j) {
        unsigned short hh = bf_rne(f[j]);
        float fh = __uint_as_float((unsigned)hh << 16);
        h[j] = hh;
        l[j] = bf_rne(f[j] - fh);
    }
    hp.x = (int)(h[0] | ((unsigned)h[1] << 16));
    hp.y = (int)(h[2] | ((unsigned)h[3] << 16));
    hp.z = (int)(h[4] | ((unsigned)h[5] << 16));
    hp.w = (int)(h[6] | ((unsigned)h[7] << 16));
    lp.x = (int)(l[0] | ((unsigned)l[1] << 16));
    lp.y = (int)(l[2] | ((unsigned)l[3] << 16));
    lp.z = (int)(l[4] | ((unsigned)l[5] << 16));
    lp.w = (int)(l[6] | ((unsigned)l[7] << 16));
}

// ------------------------------ CSR build ----------------------------------

__global__ void hist_kernel(const int* __restrict__ dst, int* __restrict__ deg, int E) {
    int i = blockIdx.x * blockDim.x + threadIdx.x;
    if (i < E) atomicAdd(&deg[dst[i]], 1);
}

// single block, shuffle-based scan; also emits float degrees and offs[n]
__global__ __launch_bounds__(256) void scan_kernel(
    const int* __restrict__ deg, int* __restrict__ offs, float* __restrict__ degf, int n) {
    __shared__ int ws[4];
    const int t = threadIdx.x;
    const int lane = t & 63;
    const int w = t >> 6;
    const int per = (n + 255) / 256;
    const int s = t * per;
    const int e = min(s + per, n);
    int sum = 0;
    for (int i = s; i < e; ++i) sum += deg[i];
    int v = sum;
#pragma unroll
    for (int off = 1; off < 64; off <<= 1) {
        int u = __shfl_up(v, off, 64);
        if (lane >= off) v += u;
    }
    if (lane == 63) ws[w] = v;
    __syncthreads();
    if (t == 0) {
        int c = 0;
#pragma unroll
        for (int i = 0; i < 4; ++i) { int x = ws[i]; ws[i] = c; c += x; }
    }
    __syncthreads();
    int run = ws[w] + v - sum;  // exclusive prefix of this thread's range
    for (int i = s; i < e; ++i) {
        int d = deg[i];
        offs[i] = run;
        degf[i] = (float)d;
        run += d;
    }
    if (e == n) offs[n] = run;  // thread(s) ending at n hold the total
}

// scatter edges into CSR order; also permutes edge features (kills eid gather)
__global__ void scatter_kernel(const int* __restrict__ src, const int* __restrict__ dst,
                               const int* __restrict__ offs, int* __restrict__ cursor,
                               int* __restrict__ csr_src, const float* __restrict__ ef,
                               float* __restrict__ ef_perm, int E) {
    int i = blockIdx.x * blockDim.x + threadIdx.x;
    if (i < E) {
        int d = dst[i];
        int pos = atomicAdd(&cursor[d], 1);
        int idx = offs[d] + pos;
        csr_src[idx] = src[i];
        const float* s6 = ef + (size_t)i * 6;
        float* d6 = ef_perm + (size_t)idx * 6;
#pragma unroll
        for (int j = 0; j < 6; ++j) d6[j] = s6[j];
    }
}

// --------------------- batched fp32 precompute GEMM ------------------------
// 22 uniform 256x256x256 products (weight-weight folds). Tiled 64x64x16.

struct PDesc { const float* A; const float* B; float* C; };
struct PTab { PDesc d[22]; };

__global__ __launch_bounds__(256) void precomp_gemm(PTab tab) {
    const PDesc d = tab.d[blockIdx.x >> 4];
    const int t = blockIdx.x & 15;
    const int rowBase = (t >> 2) * 64;
    const int colBase = (t & 3) * 64;
    __shared__ float As[16][64 + 4];
    __shared__ float Ws[16][64];
    const int tid = threadIdx.x;
    const int tx = tid & 15;
    const int ty = tid >> 4;
    float acc[4][4] = {};
    for (int kb = 0; kb < 256; kb += 16) {
        {
            int m = tid >> 2;
            int kq = (tid & 3) * 4;
            float4 v = *reinterpret_cast<const float4*>(d.A + (size_t)(rowBase + m) * 256 + kb + kq);
            As[kq + 0][m] = v.x; As[kq + 1][m] = v.y; As[kq + 2][m] = v.z; As[kq + 3][m] = v.w;
        }
        {
            int k = tid >> 4;
            int nq = (tid & 15) * 4;
            float4 v = *reinterpret_cast<const float4*>(d.B + (size_t)(kb + k) * 256 + colBase + nq);
            *reinterpret_cast<float4*>(&Ws[k][nq]) = v;
        }
        __syncthreads();
#pragma unroll
        for (int k = 0; k < 16; ++k) {
            const float4 a = *reinterpret_cast<const float4*>(&As[k][ty * 4]);
            const float4 b = *reinterpret_cast<const float4*>(&Ws[k][tx * 4]);
            float av[4] = {a.x, a.y, a.z, a.w};
            float bv[4] = {b.x, b.y, b.z, b.w};
#pragma unroll
            for (int i = 0; i < 4; ++i)
#pragma unroll
                for (int j = 0; j < 4; ++j) acc[i][j] = fmaf(av[i], bv[j], acc[i][j]);
        }
        __syncthreads();
    }
#pragma unroll
    for (int i = 0; i < 4; ++i) {
        float4 v = make_float4(acc[i][0], acc[i][1], acc[i][2], acc[i][3]);
        *reinterpret_cast<float4*>(d.C + (size_t)(rowBase + ty * 4 + i) * 256 + colBase + tx * 4) = v;
    }
}

// ----------------------- folded bias vectors -------------------------------
// out[j] = base[j] + sum_k v1[k]*B1[k*256+j] + sum_k v2[k]*B2[k*256+j]

struct BDesc { float* out; const float* base; const float* v1; const float* B1;
               const float* v2; const float* B2; };
struct BTab { BDesc d[19]; };

__global__ __launch_bounds__(256) void biasvec_kernel(BTab tab) {
    const BDesc d = tab.d[blockIdx.x];
    const int j = threadIdx.x;
    float acc = d.base ? d.base[j] : 0.f;
    if (d.v1)
        for (int k = 0; k < 256; ++k) acc = fmaf(d.v1[k], d.B1[(size_t)k * 256 + j], acc);
    if (d.v2)
        for (int k = 0; k < 256; ++k) acc = fmaf(d.v2[k], d.B2[(size_t)k * 256 + j], acc);
    d.out[j] = acc;
}

// ------------------------ weight convert (one launch) ----------------------
// src [Kreal, srcN] fp32 row-major -> dh/dl [srcN][Kpad] bf16 hi/lo.

struct CDesc {
    const float* src;
    unsigned short* dh;
    unsigned short* dl;
    int Kreal, Kpad, srcN, tile0;
};
struct CTab {
    CDesc d[32];
    int nd;
};

__global__ __launch_bounds__(256) void convert_weights(CTab tab) {
    const int bid = blockIdx.x;
    int idx = 0;
    for (int i = 1; i < tab.nd; ++i)
        if (tab.d[i].tile0 <= bid) idx = i;
    const CDesc d = tab.d[idx];
    const int q = bid - d.tile0;
    const int ntN = d.srcN >> 6;
    const int kb = (q / ntN) * 32;
    const int nb = (q % ntN) * 64;
    const int n = nb + (threadIdx.x & 63);
    const int k0 = kb + (threadIdx.x >> 6) * 8;
    float f[8];
#pragma unroll
    for (int j = 0; j < 8; ++j) {
        int k = k0 + j;
        f[j] = (k < d.Kreal) ? d.src[(size_t)k * d.srcN + n] : 0.f;
    }
    int4 hp, lp;
    split_pack8(f, hp, lp);
    *reinterpret_cast<int4*>(&d.dh[(size_t)n * d.Kpad + k0]) = hp;
    *reinterpret_cast<int4*>(&d.dl[(size_t)n * d.Kpad + k0]) = lp;
}

// ------------------------------ MFMA GEMM ----------------------------------
// C = act( A1@W1 (+ A2@W2) + bias + rowscale.*bias2 ), A fp32 split to bf16
// hi/lo in LDS, W pre-converted [Nc][K] bf16 hi/lo. 64x64 tile, BK=32,
// 4 waves (2x2), 12 MFMA/k-iter. Output fp32 (Cf) or fp16 (Ch).

#define ASTR 40

__global__ __launch_bounds__(256) void mfma_gemm(
    const float* __restrict__ A1, int lda1, const unsigned short* __restrict__ W1h,
    const unsigned short* __restrict__ W1l, int K1,
    const float* __restrict__ A2, int lda2, const unsigned short* __restrict__ W2h,
    const unsigned short* __restrict__ W2l, int K2,
    const float* __restrict__ bias, const float* __restrict__ bias2,
    const float* __restrict__ rowscale,
    float* __restrict__ Cf, __half* __restrict__ Ch, int M, int Nc, int do_relu) {
    __shared__ __align__(16) unsigned short Ah[64 * ASTR];
    __shared__ __align__(16) unsigned short Al[64 * ASTR];
    __shared__ __align__(16) unsigned short Bh[64 * ASTR];
    __shared__ __align__(16) unsigned short Bl[64 * ASTR];

    const int tid = threadIdx.x;
    const int lane = tid & 63;
    const int wave = tid >> 6;
    const int waveM = (wave >> 1) * 32;
    const int waveN = (wave & 1) * 32;
    const int m0 = lane & 15;
    const int quad = lane >> 4;
    const int rowBase = blockIdx.x * 64;
    const int colBase = blockIdx.y * 64;
    const int sr = tid >> 2;
    const int sseg = tid & 3;
    const int arow = rowBase + sr;

    const f32x4 z = {0.f, 0.f, 0.f, 0.f};
    f32x4 acc[2][2] = {{z, z}, {z, z}};

    for (int pass = 0; pass < 2; ++pass) {
        const float* A = pass ? A2 : A1;
        if (!A) continue;
        const int lda = pass ? lda2 : lda1;
        const unsigned short* Wh = pass ? W2h : W1h;
        const unsigned short* Wl = pass ? W2l : W1l;
        const int K = pass ? K2 : K1;
        const bool vec = ((lda & 3) == 0);

        for (int kb = 0; kb < K; kb += 32) {
            {
                float f[8];
                if (arow < M) {
                    const float* Ap = A + (size_t)arow * lda + kb + sseg * 8;
                    if (vec) {
                        float4 u0 = *reinterpret_cast<const float4*>(Ap);
                        float4 u1 = *reinterpret_cast<const float4*>(Ap + 4);
                        f[0] = u0.x; f[1] = u0.y; f[2] = u0.z; f[3] = u0.w;
                        f[4] = u1.x; f[5] = u1.y; f[6] = u1.z; f[7] = u1.w;
                    } else {
#pragma unroll
                        for (int j = 0; j < 8; ++j) {
                            int k = kb + sseg * 8 + j;
                            f[j] = (k < lda) ? Ap[j] : 0.f;
                        }
                    }
                } else {
#pragma unroll
                    for (int j = 0; j < 8; ++j) f[j] = 0.f;
                }
                int4 hp, lp;
                split_pack8(f, hp, lp);
                *reinterpret_cast<int4*>(&Ah[sr * ASTR + sseg * 8]) = hp;
                *reinterpret_cast<int4*>(&Al[sr * ASTR + sseg * 8]) = lp;
            }
            {
                size_t off = (size_t)(colBase + sr) * K + kb + sseg * 8;
                *reinterpret_cast<int4*>(&Bh[sr * ASTR + sseg * 8]) =
                    *reinterpret_cast<const int4*>(&Wh[off]);
                *reinterpret_cast<int4*>(&Bl[sr * ASTR + sseg * 8]) =
                    *reinterpret_cast<const int4*>(&Wl[off]);
            }
            __syncthreads();

            const short8 a0h = *reinterpret_cast<const short8*>(&Ah[(waveM + m0) * ASTR + quad * 8]);
            const short8 a1h = *reinterpret_cast<const short8*>(&Ah[(waveM + 16 + m0) * ASTR + quad * 8]);
            const short8 a0l = *reinterpret_cast<const short8*>(&Al[(waveM + m0) * ASTR + quad * 8]);
            const short8 a1l = *reinterpret_cast<const short8*>(&Al[(waveM + 16 + m0) * ASTR + quad * 8]);
            const short8 b0h = *reinterpret_cast<const short8*>(&Bh[(waveN + m0) * ASTR + quad * 8]);
            const short8 b1h = *reinterpret_cast<const short8*>(&Bh[(waveN + 16 + m0) * ASTR + quad * 8]);
            const short8 b0l = *reinterpret_cast<const short8*>(&Bl[(waveN + m0) * ASTR + quad * 8]);
            const short8 b1l = *reinterpret_cast<const short8*>(&Bl[(waveN + 16 + m0) * ASTR + quad * 8]);

            acc[0][0] = __builtin_amdgcn_mfma_f32_16x16x32_bf16(a0h, b0h, acc[0][0], 0, 0, 0);
            acc[0][1] = __builtin_amdgcn_mfma_f32_16x16x32_bf16(a0h, b1h, acc[0][1], 0, 0, 0);
            acc[1][0] = __builtin_amdgcn_mfma_f32_16x16x32_bf16(a1h, b0h, acc[1][0], 0, 0, 0);
            acc[1][1] = __builtin_amdgcn_mfma_f32_16x16x32_bf16(a1h, b1h, acc[1][1], 0, 0, 0);
            acc[0][0] = __builtin_amdgcn_mfma_f32_16x16x32_bf16(a0l, b0h, acc[0][0], 0, 0, 0);
            acc[0][1] = __builtin_amdgcn_mfma_f32_16x16x32_bf16(a0l, b1h, acc[0][1], 0, 0, 0);
            acc[1][0] = __builtin_amdgcn_mfma_f32_16x16x32_bf16(a1l, b0h, acc[1][0], 0, 0, 0);
            acc[1][1] = __builtin_amdgcn_mfma_f32_16x16x32_bf16(a1l, b1h, acc[1][1], 0, 0, 0);
            acc[0][0] = __builtin_amdgcn_mfma_f32_16x16x32_bf16(a0h, b0l, acc[0][0], 0, 0, 0);
            acc[0][1] = __builtin_amdgcn_mfma_f32_16x16x32_bf16(a0h, b1l, acc[0][1], 0, 0, 0);
            acc[1][0] = __builtin_amdgcn_mfma_f32_16x16x32_bf16(a1h, b0l, acc[1][0], 0, 0, 0);
            acc[1][1] = __builtin_amdgcn_mfma_f32_16x16x32_bf16(a1h, b1l, acc[1][1], 0, 0, 0);

            __syncthreads();
        }
    }

    // epilogue
    float cb[2] = {0.f, 0.f}, db[2] = {0.f, 0.f};
    int col[2];
#pragma unroll
    for (int tn = 0; tn < 2; ++tn) {
        col[tn] = colBase + waveN + tn * 16 + m0;
        if (bias) cb[tn] = bias[col[tn]];
        if (bias2) db[tn] = bias2[col[tn]];
    }
#pragma unroll
    for (int tm = 0; tm < 2; ++tm) {
#pragma unroll
        for (int reg = 0; reg < 4; ++reg) {
            int row = rowBase + waveM + tm * 16 + quad * 4 + reg;
            if (row >= M) continue;
            float rs = rowscale ? rowscale[row] : 0.0f;
#pragma unroll
            for (int tn = 0; tn < 2; ++tn) {
                float v = acc[tm][tn][reg] + cb[tn] + rs * db[tn];
                if (do_relu) v = fmaxf(v, 0.f);
                if (Ch)
                    Ch[(size_t)row * Nc + col[tn]] = __float2half_rn(v);
                else
                    Cf[(size_t)row * Nc + col[tn]] = v;
            }
        }
    }
}

// --------------------------- edge aggregation ------------------------------
// Hagg[v] = sum_{e=(s,v)} relu(P[s] + Q[v] + bagg + ef_e @ W1c), PQ fp16.

__global__ __launch_bounds__(256) void aggregate_kernel(
    const __half* __restrict__ PQ, const float* __restrict__ bagg,
    const float* __restrict__ ef, const int* __restrict__ offs,
    const int* __restrict__ csr_src, const float* __restrict__ W1c,
    float* __restrict__ Hagg, int n) {
    const int wave = threadIdx.x >> 6;
    const int lane = threadIdx.x & 63;
    const int node = blockIdx.x * 4 + wave;
    if (node >= n) return;
    const int col = lane * 4;

    float4 wc[6];
#pragma unroll
    for (int k = 0; k < 6; ++k) wc[k] = *reinterpret_cast<const float4*>(W1c + k * HID + col);
    float4 q;
    {
        float2 raw = *reinterpret_cast<const float2*>(PQ + (size_t)node * 512 + 256 + col);
        float2 f01 = __half22float2(*reinterpret_cast<const __half2*>(&raw.x));
        float2 f23 = __half22float2(*reinterpret_cast<const __half2*>(&raw.y));
        const float4 bb = *reinterpret_cast<const float4*>(bagg + col);
        q = make_float4(f01.x + bb.x, f01.y + bb.y, f23.x + bb.z, f23.y + bb.w);
    }
    float4 acc = make_float4(0.f, 0.f, 0.f, 0.f);

    const int beg = offs[node];
    const int end = offs[node + 1];
#pragma unroll 2
    for (int j = beg; j < end; ++j) {
        int s = csr_src[j];
        float2 raw = *reinterpret_cast<const float2*>(PQ + (size_t)s * 512 + col);
        float2 p01 = __half22float2(*reinterpret_cast<const __half2*>(&raw.x));
        float2 p23 = __half22float2(*reinterpret_cast<const __half2*>(&raw.y));
        const float* efp = ef + (size_t)j * 6;
        float e0 = efp[0], e1 = efp[1], e2 = efp[2], e3 = efp[3], e4 = efp[4], e5 = efp[5];
        float4 h;
        h.x = p01.x + q.x + e0 * wc[0].x + e1 * wc[1].x + e2 * wc[2].x + e3 * wc[3].x + e4 * wc[4].x + e5 * wc[5].x;
        h.y = p01.y + q.y + e0 * wc[0].y + e1 * wc[1].y + e2 * wc[2].y + e3 * wc[3].y + e4 * wc[4].y + e5 * wc[5].y;
        h.z = p23.x + q.z + e0 * wc[0].z + e1 * wc[1].z + e2 * wc[2].z + e3 * wc[3].z + e4 * wc[4].z + e5 * wc[5].z;
        h.w = p23.y + q.w + e0 * wc[0].w + e1 * wc[1].w + e2 * wc[2].w + e3 * wc[3].w + e4 * wc[4].w + e5 * wc[5].w;
        acc.x += fmaxf(h.x, 0.f);
        acc.y += fmaxf(h.y, 0.f);
        acc.z += fmaxf(h.z, 0.f);
        acc.w += fmaxf(h.w, 0.f);
    }
    *reinterpret_cast<float4*>(Hagg + (size_t)node * HID + col) = acc;
}

// ------------------------------- readout -----------------------------------

__global__ __launch_bounds__(256) void readout_dot_kernel(
    const float* __restrict__ h2, const float* __restrict__ w3,
    float* __restrict__ accum, int n) {
    const int wave = threadIdx.x >> 6;
    const int lane = threadIdx.x & 63;
    const int nwaves = gridDim.x * 4;
    const int wid = blockIdx.x * 4 + wave;
    const float2 w = *reinterpret_cast<const float2*>(w3 + lane * 2);
    float local = 0.f;
    for (int node = wid; node < n; node += nwaves) {
        const float2 v = *reinterpret_cast<const float2*>(h2 + (size_t)node * 128 + lane * 2);
        local = fmaf(v.x, w.x, local);
        local = fmaf(v.y, w.y, local);
    }
    for (int off = 32; off > 0; off >>= 1) local += __shfl_down(local, off, 64);
    if (lane == 0) atomicAdd(accum, local);
}

__global__ void finalize_kernel(const float* __restrict__ accum, const float* __restrict__ b3,
                                float* __restrict__ out, float inv_n) {
    out[0] = accum[0] * inv_n + b3[0];
}

// ------------------------------- driver ------------------------------------

extern "C" void kernel_launch(void* const* d_in, const int* in_sizes, int n_in,
                              void* d_out, int out_size, void* d_ws, size_t ws_size,
                              hipStream_t stream) {
    const float* atom   = (const float*)d_in[0];   // [N,62]
    const int*   eidx   = (const int*)d_in[1];     // [2,E]
    const float* ef     = (const float*)d_in[2];   // [E,6]
    const float* emb_w  = (const float*)d_in[3];   // [62,256]
    const float* emb_b  = (const float*)d_in[4];   // [256]
    const float* msg_w1 = (const float*)d_in[5];   // [L,518,256]
    const float* msg_b1 = (const float*)d_in[6];   // [L,256]
    const float* msg_w2 = (const float*)d_in[7];   // [L,256,256]
    const float* msg_b2 = (const float*)d_in[8];   // [L,256]
    const float* upd_w1 = (const float*)d_in[9];   // [L,512,256]
    const float* upd_b1 = (const float*)d_in[10];  // [L,256]
    const float* upd_w2 = (const float*)d_in[11];  // [L,256,256]
    const float* upd_b2 = (const float*)d_in[12];  // [L,256]
    const float* r_w1   = (const float*)d_in[13];  // [256,256]
    const float* r_b1   = (const float*)d_in[14];
    const float* r_w2   = (const float*)d_in[15];  // [256,128]
    const float* r_b2   = (const float*)d_in[16];
    const float* r_w3   = (const float*)d_in[17];  // [128,1]
    const float* r_b3   = (const float*)d_in[18];

    const int N = in_sizes[0] / 62;
    const int E = in_sizes[1] / 2;
    const int L = in_sizes[5] / (518 * 256);
    const int* src = eidx;
    const int* dst = eidx + E;

    char* wp = (char*)d_ws;
    auto alloc = [&](size_t bytes) -> void* {
        void* p = (void*)wp;
        wp += (bytes + 255) & ~(size_t)255;
        return p;
    };
    int*   deg     = (int*)alloc((size_t)N * 4);
    int*   cursor  = (int*)alloc((size_t)N * 4);
    float* accum   = (float*)alloc(256);
    size_t zero_bytes = (size_t)((char*)accum - (char*)d_ws) + 256;
    float* degf    = (float*)alloc((size_t)N * 4);
    int*   offs    = (int*)alloc((size_t)(N + 1) * 4);
    int*   csr_src = (int*)alloc((size_t)E * 4);
    float* ef_perm = (float*)alloc((size_t)E * 6 * 4);

    // converted weight planes (bf16 hi/lo, [Nc][Kpad])
    const int EMB_P = 256 * 64, PQ_P = 512 * 256, SQ_P = 256 * 256, R2_P = 128 * 256;
    unsigned short* w_emb = (unsigned short*)alloc((size_t)EMB_P * 2 * 2);
    unsigned short* w_xu0 = (unsigned short*)alloc((size_t)SQ_P * 2 * 2);
    unsigned short* w_r2  = (unsigned short*)alloc((size_t)R2_P * 2 * 2);
    unsigned short* wF    = (unsigned short*)alloc((size_t)SQ_P * 2 * 2);
    unsigned short *wPQ[6], *wM2_[6], *wM3_[6];
    for (int l = 0; l < L; ++l) {
        wPQ[l]  = (unsigned short*)alloc((size_t)PQ_P * 2 * 2);
        wM2_[l] = (unsigned short*)alloc((size_t)SQ_P * 2 * 2);
        wM3_[l] = (unsigned short*)alloc((size_t)SQ_P * 2 * 2);
    }
    // precompute scratch: 22 x [256,256] fp32
    float* pscr = (float*)alloc((size_t)22 * 65536 * 4);
    // folded bias vectors: [0..5]=bagg, [6..11]=cb_u, [12..17]=db, [18]=cb_r
    float* bvec = (float*)alloc((size_t)19 * 256 * 4);

    float* bufX0 = (float*)alloc((size_t)N * HID * 4);
    float* bufX1 = (float*)alloc((size_t)N * HID * 4);
    __half* PQh  = (__half*)alloc((size_t)N * 512 * 2);
    float* Hagg  = (float*)alloc((size_t)N * HID * 4);

    hipMemsetAsync(d_ws, 0, zero_bytes, stream);

    // ---- CSR build ----
    hist_kernel<<<(E + 255) / 256, 256, 0, stream>>>(dst, deg, E);
    scan_kernel<<<1, 256, 0, stream>>>(deg, offs, degf, N);
    scatter_kernel<<<(E + 255) / 256, 256, 0, stream>>>(src, dst, offs, cursor,
                                                        csr_src, ef, ef_perm, E);

    // ---- weight-weight folds (fp32) ----
    // slots: 0..4 M1a[l=1..5], 5..9 M1b[l=1..5], 10..14 M2[l=1..5],
    //        15..20 M3[l=0..5], 21 F
    PTab pt;
    for (int l = 1; l < L; ++l) {
        const float* U2p = upd_w2 + (size_t)(l - 1) * SQ_P;
        pt.d[l - 1]      = {U2p, msg_w1 + (size_t)l * 518 * 256,             pscr + (size_t)(l - 1) * 65536};
        pt.d[4 + l]      = {U2p, msg_w1 + (size_t)l * 518 * 256 + 256 * 256, pscr + (size_t)(4 + l) * 65536};
        pt.d[9 + l]      = {U2p, upd_w1 + (size_t)l * 512 * 256,             pscr + (size_t)(9 + l) * 65536};
    }
    for (int l = 0; l < L; ++l)
        pt.d[15 + l] = {msg_w2 + (size_t)l * SQ_P, upd_w1 + (size_t)l * 512 * 256 + 256 * 256,
                        pscr + (size_t)(15 + l) * 65536};
    pt.d[21] = {upd_w2 + (size_t)5 * SQ_P, r_w1, pscr + (size_t)21 * 65536};
    precomp_gemm<<<22 * 16, 256, 0, stream>>>(pt);

    // ---- convert all GEMM weights to bf16 hi/lo planes (one launch) ----
    CTab ct;
    int nd = 0, tiles = 0;
    auto addDesc = [&](const float* s, unsigned short* dh, unsigned short* dl,
                       int Kreal, int Kpad, int srcN) {
        ct.d[nd] = {s, dh, dl, Kreal, Kpad, srcN, tiles};
        tiles += (Kpad / 32) * (srcN / 64);
        ++nd;
    };
    addDesc(emb_w, w_emb, w_emb + EMB_P, 62, 64, 256);
    addDesc(msg_w1, wPQ[0], wPQ[0] + PQ_P, 256, 256, 256);                       // W1a_0
    addDesc(msg_w1 + 256 * 256, wPQ[0] + SQ_P, wPQ[0] + PQ_P + SQ_P, 256, 256, 256); // W1b_0
    addDesc(upd_w1, w_xu0, w_xu0 + SQ_P, 256, 256, 256);                         // U1a_0
    addDesc(r_w2, w_r2, w_r2 + R2_P, 256, 256, 128);
    for (int l = 1; l < L; ++l) {
        addDesc(pscr + (size_t)(l - 1) * 65536, wPQ[l], wPQ[l] + PQ_P, 256, 256, 256);
        addDesc(pscr + (size_t)(4 + l) * 65536, wPQ[l] + SQ_P, wPQ[l] + PQ_P + SQ_P, 256, 256, 256);
        addDesc(pscr + (size_t)(9 + l) * 65536, wM2_[l], wM2_[l] + SQ_P, 256, 256, 256);
    }
    for (int l = 0; l < L; ++l)
        addDesc(pscr + (size_t)(15 + l) * 65536, wM3_[l], wM3_[l] + SQ_P, 256, 256, 256);
    addDesc(pscr + (size_t)21 * 65536, wF, wF + SQ_P, 256, 256, 256);
    ct.nd = nd;
    convert_weights<<<tiles, 256, 0, stream>>>(ct);

    // ---- folded bias vectors ----
    BTab bt;
    for (int l = 0; l < L; ++l) {
        const float* ub2p = (l > 0) ? upd_b2 + (size_t)(l - 1) * 256 : nullptr;
        // bagg[l] = b1 + ub2_{l-1}@W1a + ub2_{l-1}@W1b
        bt.d[l] = {bvec + (size_t)l * 256, msg_b1 + (size_t)l * 256,
                   ub2p, msg_w1 + (size_t)l * 518 * 256,
                   ub2p, msg_w1 + (size_t)l * 518 * 256 + 256 * 256};
        // cb_u[l] = ub1 + ub2_{l-1}@U1a
        bt.d[6 + l] = {bvec + (size_t)(6 + l) * 256, upd_b1 + (size_t)l * 256,
                       ub2p, upd_w1 + (size_t)l * 512 * 256, nullptr, nullptr};
        // db[l] = b2@U1b
        bt.d[12 + l] = {bvec + (size_t)(12 + l) * 256, nullptr,
                        msg_b2 + (size_t)l * 256, upd_w1 + (size_t)l * 512 * 256 + 256 * 256,
                        nullptr, nullptr};
    }
    // cb_r = r_b1 + ub2_5@r_w1
    bt.d[18] = {bvec + (size_t)18 * 256, r_b1, upd_b2 + (size_t)5 * 256, r_w1,
                nullptr, nullptr};
    biasvec_kernel<<<19, 256, 0, stream>>>(bt);

    const int mblk = (N + 63) / 64;
    dim3 blk(256);

    // embed: x0 = atom @ emb_w + emb_b
    mfma_gemm<<<dim3(mblk, 4), blk, 0, stream>>>(
        atom, 62, w_emb, w_emb + EMB_P, 64,
        nullptr, 0, nullptr, nullptr, 0,
        emb_b, nullptr, nullptr, bufX0, nullptr, N, HID, 0);

    float* U_prev = bufX0;
    float* U_next = bufX1;
    for (int l = 0; l < L; ++l) {
        const float* w1c = msg_w1 + (size_t)l * 518 * 256 + 512 * 256;
        const unsigned short* xu = (l == 0) ? w_xu0 : wM2_[l];

        // PQ = U_prev @ [M1a | M1b]  (fp16 out; all biases folded downstream)
        mfma_gemm<<<dim3(mblk, 8), blk, 0, stream>>>(
            U_prev, HID, wPQ[l], wPQ[l] + PQ_P, HID,
            nullptr, 0, nullptr, nullptr, 0,
            nullptr, nullptr, nullptr, nullptr, PQh, N, 512, 0);
        // Hagg[v] = sum_e relu(P[src]+Q[v]+bagg+ef@W1c)
        aggregate_kernel<<<(N + 3) / 4, blk, 0, stream>>>(
            PQh, bvec + (size_t)l * 256, ef_perm, offs, csr_src, w1c, Hagg, N);
        // U = relu(U_prev@M2 + Hagg@M3 + cb_u + deg.*db)
        mfma_gemm<<<dim3(mblk, 4), blk, 0, stream>>>(
            U_prev, HID, xu, xu + SQ_P, HID,
            Hagg, HID, wM3_[l], wM3_[l] + SQ_P, HID,
            bvec + (size_t)(6 + l) * 256, bvec + (size_t)(12 + l) * 256, degf,
            U_next, nullptr, N, HID, 1);
        float* t = U_prev; U_prev = U_next; U_next = t;
    }

    // readout: h1 = relu(U5@F + cb_r); h2 = relu(h1@r_w2 + r_b2); mean dot
    mfma_gemm<<<dim3(mblk, 4), blk, 0, stream>>>(
        U_prev, HID, wF, wF + SQ_P, HID,
        nullptr, 0, nullptr, nullptr, 0,
        bvec + (size_t)18 * 256, nullptr, nullptr, U_next, nullptr, N, HID, 1);
    mfma_gemm<<<dim3(mblk, 2), blk, 0, stream>>>(
        U_next, HID, w_r2, w_r2 + R2_P, HID,
        nullptr, 0, nullptr, nullptr, 0,
        r_b2, nullptr, nullptr, Hagg, nullptr, N, 128, 1);
    readout_dot_kernel<<<256, blk, 0, stream>>>(Hagg, r_w3, accum, N);
    finalize_kernel<<<1, 1, 0, stream>>>(accum, r_b3, (float*)d_out, 1.0f / (float)N);
}

// Round 4
// 613.502 us; speedup vs baseline: 2.3614x; 1.0651x over previous
//
#include <hip/hip_runtime.h>
#include <hip/hip_bf16.h>
#include <hip/hip_fp16.h>

// ---------------------------------------------------------------------------
// MPNN binding-affinity predictor. R4:
//  - aggregate: 2 edges/wave (half-wave int4 gathers), ef packed fp16x8
//  - all activations fp16 (exact split into bf16 hi/lo for 3-MFMA emulation)
//  - weight-weight folds moved to matrix cores (one batched launch)
// ---------------------------------------------------------------------------

#define HID 256

typedef short short8 __attribute__((ext_vector_type(8)));
typedef float f32x4 __attribute__((ext_vector_type(4)));

__device__ __forceinline__ unsigned short bf_rne(float f) {
    unsigned u = __float_as_uint(f);
    u += 0x7fffu + ((u >> 16) & 1u);
    return (unsigned short)(u >> 16);
}

__device__ __forceinline__ void split_pack8(const float* f, int4& hp, int4& lp) {
    unsigned short h[8], l[8];
#pragma unroll
    for (int j = 0; j < 8; ++j) {
        unsigned short hh = bf_rne(f[j]);
        float fh = __uint_as_float((unsigned)hh << 16);
        h[j] = hh;
        l[j] = bf_rne(f[j] - fh);
    }
    hp.x = (int)(h[0] | ((unsigned)h[1] << 16));
    hp.y = (int)(h[2] | ((unsigned)h[3] << 16));
    hp.z = (int)(h[4] | ((unsigned)h[5] << 16));
    hp.w = (int)(h[6] | ((unsigned)h[7] << 16));
    lp.x = (int)(l[0] | ((unsigned)l[1] << 16));
    lp.y = (int)(l[2] | ((unsigned)l[3] << 16));
    lp.z = (int)(l[4] | ((unsigned)l[5] << 16));
    lp.w = (int)(l[6] | ((unsigned)l[7] << 16));
}

__device__ __forceinline__ void unpack_h8(const int4& r, float* f) {
    const __half2* h = reinterpret_cast<const __half2*>(&r);
#pragma unroll
    for (int k = 0; k < 4; ++k) {
        float2 t = __half22float2(h[k]);
        f[2 * k] = t.x;
        f[2 * k + 1] = t.y;
    }
}

// ------------------------------ CSR build ----------------------------------

__global__ void hist_kernel(const int* __restrict__ dst, int* __restrict__ deg, int E) {
    int i = blockIdx.x * blockDim.x + threadIdx.x;
    if (i < E) atomicAdd(&deg[dst[i]], 1);
}

__global__ __launch_bounds__(256) void scan_kernel(
    const int* __restrict__ deg, int* __restrict__ offs, float* __restrict__ degf, int n) {
    __shared__ int ws[4];
    const int t = threadIdx.x;
    const int lane = t & 63;
    const int w = t >> 6;
    const int per = (n + 255) / 256;
    const int s = t * per;
    const int e = min(s + per, n);
    int sum = 0;
    for (int i = s; i < e; ++i) sum += deg[i];
    int v = sum;
#pragma unroll
    for (int off = 1; off < 64; off <<= 1) {
        int u = __shfl_up(v, off, 64);
        if (lane >= off) v += u;
    }
    if (lane == 63) ws[w] = v;
    __syncthreads();
    if (t == 0) {
        int c = 0;
#pragma unroll
        for (int i = 0; i < 4; ++i) { int x = ws[i]; ws[i] = c; c += x; }
    }
    __syncthreads();
    int run = ws[w] + v - sum;
    for (int i = s; i < e; ++i) {
        int d = deg[i];
        offs[i] = run;
        degf[i] = (float)d;
        run += d;
    }
    if (e == n) offs[n] = run;
}

// scatter edges into CSR order; ef packed to fp16x8 (16B aligned per edge)
__global__ void scatter_kernel(const int* __restrict__ src, const int* __restrict__ dst,
                               const int* __restrict__ offs, int* __restrict__ cursor,
                               int* __restrict__ csr_src, const float* __restrict__ ef,
                               __half* __restrict__ ef8, int E) {
    int i = blockIdx.x * blockDim.x + threadIdx.x;
    if (i < E) {
        int d = dst[i];
        int pos = atomicAdd(&cursor[d], 1);
        int idx = offs[d] + pos;
        csr_src[idx] = src[i];
        const float* s6 = ef + (size_t)i * 6;
        unsigned short h[8];
#pragma unroll
        for (int j = 0; j < 6; ++j) h[j] = __half_as_ushort(__float2half_rn(s6[j]));
        h[6] = 0; h[7] = 0;
        int4 pk;
        pk.x = (int)(h[0] | ((unsigned)h[1] << 16));
        pk.y = (int)(h[2] | ((unsigned)h[3] << 16));
        pk.z = (int)(h[4] | ((unsigned)h[5] << 16));
        pk.w = (int)(h[6] | ((unsigned)h[7] << 16));
        *reinterpret_cast<int4*>(ef8 + (size_t)idx * 8) = pk;
    }
}

// ----------------------- folded bias vectors -------------------------------

struct BDesc { float* out; const float* base; const float* v1; const float* B1;
               const float* v2; const float* B2; };
struct BTab { BDesc d[19]; };

__global__ __launch_bounds__(256) void biasvec_kernel(BTab tab) {
    const BDesc d = tab.d[blockIdx.x];
    const int j = threadIdx.x;
    float acc = d.base ? d.base[j] : 0.f;
    if (d.v1)
        for (int k = 0; k < 256; ++k) acc = fmaf(d.v1[k], d.B1[(size_t)k * 256 + j], acc);
    if (d.v2)
        for (int k = 0; k < 256; ++k) acc = fmaf(d.v2[k], d.B2[(size_t)k * 256 + j], acc);
    d.out[j] = acc;
}

// ------------------------ weight convert -----------------------------------
// src [Kreal, srcN] fp32 row-major -> dh/dl [srcN][Kpad] bf16 hi/lo.

struct CDesc {
    const float* src;
    unsigned short* dh;
    unsigned short* dl;
    int Kreal, Kpad, srcN, tile0;
};
struct CTab {
    CDesc d[32];
    int nd;
};

__global__ __launch_bounds__(256) void convert_weights(CTab tab) {
    const int bid = blockIdx.x;
    int idx = 0;
    for (int i = 1; i < tab.nd; ++i)
        if (tab.d[i].tile0 <= bid) idx = i;
    const CDesc d = tab.d[idx];
    const int q = bid - d.tile0;
    const int ntN = d.srcN >> 6;
    const int kb = (q / ntN) * 32;
    const int nb = (q % ntN) * 64;
    const int n = nb + (threadIdx.x & 63);
    const int k0 = kb + (threadIdx.x >> 6) * 8;
    float f[8];
#pragma unroll
    for (int j = 0; j < 8; ++j) {
        int k = k0 + j;
        f[j] = (k < d.Kreal) ? d.src[(size_t)k * d.srcN + n] : 0.f;
    }
    int4 hp, lp;
    split_pack8(f, hp, lp);
    *reinterpret_cast<int4*>(&d.dh[(size_t)n * d.Kpad + k0]) = hp;
    *reinterpret_cast<int4*>(&d.dl[(size_t)n * d.Kpad + k0]) = lp;
}

// ------------------- batched fold GEMM on matrix cores ---------------------
// C[256,256] = A[256,256](fp32) @ B(pre-converted bf16 hi/lo [n][k]).
// 22 descs x 16 tiles of 64x64. Same 3-MFMA split scheme as mfma_gemm.

#define ASTR 40

struct FDesc { const float* A; const unsigned short* Bh; const unsigned short* Bl; float* C; };
struct FTab { FDesc d[22]; };

__global__ __launch_bounds__(256) void fold_gemm(FTab tab) {
    const FDesc dd = tab.d[blockIdx.x >> 4];
    const int t4 = blockIdx.x & 15;
    const int rowBase = (t4 >> 2) * 64;
    const int colBase = (t4 & 3) * 64;

    __shared__ __align__(16) unsigned short Ah[64 * ASTR];
    __shared__ __align__(16) unsigned short Al[64 * ASTR];
    __shared__ __align__(16) unsigned short Bh[64 * ASTR];
    __shared__ __align__(16) unsigned short Bl[64 * ASTR];

    const int tid = threadIdx.x;
    const int lane = tid & 63;
    const int wave = tid >> 6;
    const int waveM = (wave >> 1) * 32;
    const int waveN = (wave & 1) * 32;
    const int m0 = lane & 15;
    const int quad = lane >> 4;
    const int sr = tid >> 2;
    const int sseg = tid & 3;

    const f32x4 z = {0.f, 0.f, 0.f, 0.f};
    f32x4 acc[2][2] = {{z, z}, {z, z}};

    for (int kb = 0; kb < 256; kb += 32) {
        {
            const float* Ap = dd.A + (size_t)(rowBase + sr) * 256 + kb + sseg * 8;
            float f[8];
            float4 u0 = *reinterpret_cast<const float4*>(Ap);
            float4 u1 = *reinterpret_cast<const float4*>(Ap + 4);
            f[0] = u0.x; f[1] = u0.y; f[2] = u0.z; f[3] = u0.w;
            f[4] = u1.x; f[5] = u1.y; f[6] = u1.z; f[7] = u1.w;
            int4 hp, lp;
            split_pack8(f, hp, lp);
            *reinterpret_cast<int4*>(&Ah[sr * ASTR + sseg * 8]) = hp;
            *reinterpret_cast<int4*>(&Al[sr * ASTR + sseg * 8]) = lp;
        }
        {
            size_t off = (size_t)(colBase + sr) * 256 + kb + sseg * 8;
            *reinterpret_cast<int4*>(&Bh[sr * ASTR + sseg * 8]) =
                *reinterpret_cast<const int4*>(&dd.Bh[off]);
            *reinterpret_cast<int4*>(&Bl[sr * ASTR + sseg * 8]) =
                *reinterpret_cast<const int4*>(&dd.Bl[off]);
        }
        __syncthreads();

        const short8 a0h = *reinterpret_cast<const short8*>(&Ah[(waveM + m0) * ASTR + quad * 8]);
        const short8 a1h = *reinterpret_cast<const short8*>(&Ah[(waveM + 16 + m0) * ASTR + quad * 8]);
        const short8 a0l = *reinterpret_cast<const short8*>(&Al[(waveM + m0) * ASTR + quad * 8]);
        const short8 a1l = *reinterpret_cast<const short8*>(&Al[(waveM + 16 + m0) * ASTR + quad * 8]);
        const short8 b0h = *reinterpret_cast<const short8*>(&Bh[(waveN + m0) * ASTR + quad * 8]);
        const short8 b1h = *reinterpret_cast<const short8*>(&Bh[(waveN + 16 + m0) * ASTR + quad * 8]);
        const short8 b0l = *reinterpret_cast<const short8*>(&Bl[(waveN + m0) * ASTR + quad * 8]);
        const short8 b1l = *reinterpret_cast<const short8*>(&Bl[(waveN + 16 + m0) * ASTR + quad * 8]);

        acc[0][0] = __builtin_amdgcn_mfma_f32_16x16x32_bf16(a0h, b0h, acc[0][0], 0, 0, 0);
        acc[0][1] = __builtin_amdgcn_mfma_f32_16x16x32_bf16(a0h, b1h, acc[0][1], 0, 0, 0);
        acc[1][0] = __builtin_amdgcn_mfma_f32_16x16x32_bf16(a1h, b0h, acc[1][0], 0, 0, 0);
        acc[1][1] = __builtin_amdgcn_mfma_f32_16x16x32_bf16(a1h, b1h, acc[1][1], 0, 0, 0);
        acc[0][0] = __builtin_amdgcn_mfma_f32_16x16x32_bf16(a0l, b0h, acc[0][0], 0, 0, 0);
        acc[0][1] = __builtin_amdgcn_mfma_f32_16x16x32_bf16(a0l, b1h, acc[0][1], 0, 0, 0);
        acc[1][0] = __builtin_amdgcn_mfma_f32_16x16x32_bf16(a1l, b0h, acc[1][0], 0, 0, 0);
        acc[1][1] = __builtin_amdgcn_mfma_f32_16x16x32_bf16(a1l, b1h, acc[1][1], 0, 0, 0);
        acc[0][0] = __builtin_amdgcn_mfma_f32_16x16x32_bf16(a0h, b0l, acc[0][0], 0, 0, 0);
        acc[0][1] = __builtin_amdgcn_mfma_f32_16x16x32_bf16(a0h, b1l, acc[0][1], 0, 0, 0);
        acc[1][0] = __builtin_amdgcn_mfma_f32_16x16x32_bf16(a1h, b0l, acc[1][0], 0, 0, 0);
        acc[1][1] = __builtin_amdgcn_mfma_f32_16x16x32_bf16(a1h, b1l, acc[1][1], 0, 0, 0);

        __syncthreads();
    }

#pragma unroll
    for (int tm = 0; tm < 2; ++tm)
#pragma unroll
        for (int reg = 0; reg < 4; ++reg) {
            int row = rowBase + waveM + tm * 16 + quad * 4 + reg;
#pragma unroll
            for (int tn = 0; tn < 2; ++tn) {
                int col = colBase + waveN + tn * 16 + m0;
                dd.C[(size_t)row * 256 + col] = acc[tm][tn][reg];
            }
        }
}

// ------------------------------ MFMA GEMM ----------------------------------
// C = act( A1@W1 (+ A2@W2) + bias + rowscale.*bias2 ), A fp32 or fp16
// (split to bf16 hi/lo in LDS), W pre-converted [Nc][K] bf16 hi/lo.
// 64x64 tile, BK=32, 4 waves, 12 MFMA/k-iter. Output fp32 or fp16.

__global__ __launch_bounds__(256) void mfma_gemm(
    const void* __restrict__ A1, int lda1, int a1half,
    const unsigned short* __restrict__ W1h, const unsigned short* __restrict__ W1l, int K1,
    const void* __restrict__ A2, int lda2, int a2half,
    const unsigned short* __restrict__ W2h, const unsigned short* __restrict__ W2l, int K2,
    const float* __restrict__ bias, const float* __restrict__ bias2,
    const float* __restrict__ rowscale,
    float* __restrict__ Cf, __half* __restrict__ Ch, int M, int Nc, int do_relu) {
    __shared__ __align__(16) unsigned short Ah[64 * ASTR];
    __shared__ __align__(16) unsigned short Al[64 * ASTR];
    __shared__ __align__(16) unsigned short Bh[64 * ASTR];
    __shared__ __align__(16) unsigned short Bl[64 * ASTR];

    const int tid = threadIdx.x;
    const int lane = tid & 63;
    const int wave = tid >> 6;
    const int waveM = (wave >> 1) * 32;
    const int waveN = (wave & 1) * 32;
    const int m0 = lane & 15;
    const int quad = lane >> 4;
    const int rowBase = blockIdx.x * 64;
    const int colBase = blockIdx.y * 64;
    const int sr = tid >> 2;
    const int sseg = tid & 3;
    const int arow = rowBase + sr;

    const f32x4 z = {0.f, 0.f, 0.f, 0.f};
    f32x4 acc[2][2] = {{z, z}, {z, z}};

    for (int pass = 0; pass < 2; ++pass) {
        const void* A = pass ? A2 : A1;
        if (!A) continue;
        const int lda = pass ? lda2 : lda1;
        const int ah = pass ? a2half : a1half;
        const unsigned short* Wh = pass ? W2h : W1h;
        const unsigned short* Wl = pass ? W2l : W1l;
        const int K = pass ? K2 : K1;
        const bool vec = ((lda & 3) == 0);

        for (int kb = 0; kb < K; kb += 32) {
            {
                float f[8];
                if (arow < M) {
                    if (ah) {
                        const __half* Ap = (const __half*)A + (size_t)arow * lda + kb + sseg * 8;
                        int4 r = *reinterpret_cast<const int4*>(Ap);
                        unpack_h8(r, f);
                    } else {
                        const float* Ap = (const float*)A + (size_t)arow * lda + kb + sseg * 8;
                        if (vec) {
                            float4 u0 = *reinterpret_cast<const float4*>(Ap);
                            float4 u1 = *reinterpret_cast<const float4*>(Ap + 4);
                            f[0] = u0.x; f[1] = u0.y; f[2] = u0.z; f[3] = u0.w;
                            f[4] = u1.x; f[5] = u1.y; f[6] = u1.z; f[7] = u1.w;
                        } else {
#pragma unroll
                            for (int j = 0; j < 8; ++j) {
                                int k = kb + sseg * 8 + j;
                                f[j] = (k < lda) ? Ap[j] : 0.f;
                            }
                        }
                    }
                } else {
#pragma unroll
                    for (int j = 0; j < 8; ++j) f[j] = 0.f;
                }
                int4 hp, lp;
                split_pack8(f, hp, lp);
                *reinterpret_cast<int4*>(&Ah[sr * ASTR + sseg * 8]) = hp;
                *reinterpret_cast<int4*>(&Al[sr * ASTR + sseg * 8]) = lp;
            }
            {
                size_t off = (size_t)(colBase + sr) * K + kb + sseg * 8;
                *reinterpret_cast<int4*>(&Bh[sr * ASTR + sseg * 8]) =
                    *reinterpret_cast<const int4*>(&Wh[off]);
                *reinterpret_cast<int4*>(&Bl[sr * ASTR + sseg * 8]) =
                    *reinterpret_cast<const int4*>(&Wl[off]);
            }
            __syncthreads();

            const short8 a0h = *reinterpret_cast<const short8*>(&Ah[(waveM + m0) * ASTR + quad * 8]);
            const short8 a1h = *reinterpret_cast<const short8*>(&Ah[(waveM + 16 + m0) * ASTR + quad * 8]);
            const short8 a0l = *reinterpret_cast<const short8*>(&Al[(waveM + m0) * ASTR + quad * 8]);
            const short8 a1l = *reinterpret_cast<const short8*>(&Al[(waveM + 16 + m0) * ASTR + quad * 8]);
            const short8 b0h = *reinterpret_cast<const short8*>(&Bh[(waveN + m0) * ASTR + quad * 8]);
            const short8 b1h = *reinterpret_cast<const short8*>(&Bh[(waveN + 16 + m0) * ASTR + quad * 8]);
            const short8 b0l = *reinterpret_cast<const short8*>(&Bl[(waveN + m0) * ASTR + quad * 8]);
            const short8 b1l = *reinterpret_cast<const short8*>(&Bl[(waveN + 16 + m0) * ASTR + quad * 8]);

            acc[0][0] = __builtin_amdgcn_mfma_f32_16x16x32_bf16(a0h, b0h, acc[0][0], 0, 0, 0);
            acc[0][1] = __builtin_amdgcn_mfma_f32_16x16x32_bf16(a0h, b1h, acc[0][1], 0, 0, 0);
            acc[1][0] = __builtin_amdgcn_mfma_f32_16x16x32_bf16(a1h, b0h, acc[1][0], 0, 0, 0);
            acc[1][1] = __builtin_amdgcn_mfma_f32_16x16x32_bf16(a1h, b1h, acc[1][1], 0, 0, 0);
            acc[0][0] = __builtin_amdgcn_mfma_f32_16x16x32_bf16(a0l, b0h, acc[0][0], 0, 0, 0);
            acc[0][1] = __builtin_amdgcn_mfma_f32_16x16x32_bf16(a0l, b1h, acc[0][1], 0, 0, 0);
            acc[1][0] = __builtin_amdgcn_mfma_f32_16x16x32_bf16(a1l, b0h, acc[1][0], 0, 0, 0);
            acc[1][1] = __builtin_amdgcn_mfma_f32_16x16x32_bf16(a1l, b1h, acc[1][1], 0, 0, 0);
            acc[0][0] = __builtin_amdgcn_mfma_f32_16x16x32_bf16(a0h, b0l, acc[0][0], 0, 0, 0);
            acc[0][1] = __builtin_amdgcn_mfma_f32_16x16x32_bf16(a0h, b1l, acc[0][1], 0, 0, 0);
            acc[1][0] = __builtin_amdgcn_mfma_f32_16x16x32_bf16(a1h, b0l, acc[1][0], 0, 0, 0);
            acc[1][1] = __builtin_amdgcn_mfma_f32_16x16x32_bf16(a1h, b1l, acc[1][1], 0, 0, 0);

            __syncthreads();
        }
    }

    // epilogue
    float cb[2] = {0.f, 0.f}, db[2] = {0.f, 0.f};
    int col[2];
#pragma unroll
    for (int tn = 0; tn < 2; ++tn) {
        col[tn] = colBase + waveN + tn * 16 + m0;
        if (bias) cb[tn] = bias[col[tn]];
        if (bias2) db[tn] = bias2[col[tn]];
    }
#pragma unroll
    for (int tm = 0; tm < 2; ++tm) {
#pragma unroll
        for (int reg = 0; reg < 4; ++reg) {
            int row = rowBase + waveM + tm * 16 + quad * 4 + reg;
            if (row >= M) continue;
            float rs = rowscale ? rowscale[row] : 0.0f;
#pragma unroll
            for (int tn = 0; tn < 2; ++tn) {
                float v = acc[tm][tn][reg] + cb[tn] + rs * db[tn];
                if (do_relu) v = fmaxf(v, 0.f);
                if (Ch)
                    Ch[(size_t)row * Nc + col[tn]] = __float2half_rn(v);
                else
                    Cf[(size_t)row * Nc + col[tn]] = v;
            }
        }
    }
}

// --------------------------- edge aggregation ------------------------------
// Hagg[v] = sum_{e=(s,v)} relu(P[s] + Q[v] + bagg + ef_e @ W1c).
// One wave/node; 2 half-waves process alternate edges; lane covers 8 ch.
// PQ fp16 [N][512] (P=0..255, Q=256..511); ef fp16x8; Hagg fp16 out.

__global__ __launch_bounds__(256) void aggregate_kernel(
    const __half* __restrict__ PQ, const float* __restrict__ bagg,
    const __half* __restrict__ ef8, const int* __restrict__ offs,
    const int* __restrict__ csr_src, const float* __restrict__ W1c,
    __half* __restrict__ Hagg, int n) {
    const int wave = threadIdx.x >> 6;
    const int lane = threadIdx.x & 63;
    const int node = blockIdx.x * 4 + wave;
    if (node >= n) return;
    const int hw = lane >> 5;
    const int sl = lane & 31;
    const int ch = sl * 8;

    float wc[6][8];
#pragma unroll
    for (int k = 0; k < 6; ++k) {
        float4 w0 = *reinterpret_cast<const float4*>(W1c + k * HID + ch);
        float4 w1 = *reinterpret_cast<const float4*>(W1c + k * HID + ch + 4);
        wc[k][0] = w0.x; wc[k][1] = w0.y; wc[k][2] = w0.z; wc[k][3] = w0.w;
        wc[k][4] = w1.x; wc[k][5] = w1.y; wc[k][6] = w1.z; wc[k][7] = w1.w;
    }
    float qb[8];
    {
        int4 r = *reinterpret_cast<const int4*>(PQ + (size_t)node * 512 + 256 + ch);
        unpack_h8(r, qb);
        float4 b0 = *reinterpret_cast<const float4*>(bagg + ch);
        float4 b1 = *reinterpret_cast<const float4*>(bagg + ch + 4);
        qb[0] += b0.x; qb[1] += b0.y; qb[2] += b0.z; qb[3] += b0.w;
        qb[4] += b1.x; qb[5] += b1.y; qb[6] += b1.z; qb[7] += b1.w;
    }
    float acc[8] = {0.f, 0.f, 0.f, 0.f, 0.f, 0.f, 0.f, 0.f};

    const int beg = offs[node];
    const int end = offs[node + 1];
#pragma unroll 2
    for (int j = beg + hw; j < end; j += 2) {
        int s = csr_src[j];
        int4 praw = *reinterpret_cast<const int4*>(PQ + (size_t)s * 512 + ch);
        int4 eraw = *reinterpret_cast<const int4*>(ef8 + (size_t)j * 8);
        float p[8], e[8];
        unpack_h8(praw, p);
        unpack_h8(eraw, e);
#pragma unroll
        for (int i = 0; i < 8; ++i) {
            float h = p[i] + qb[i];
            h = fmaf(e[0], wc[0][i], h);
            h = fmaf(e[1], wc[1][i], h);
            h = fmaf(e[2], wc[2][i], h);
            h = fmaf(e[3], wc[3][i], h);
            h = fmaf(e[4], wc[4][i], h);
            h = fmaf(e[5], wc[5][i], h);
            acc[i] += fmaxf(h, 0.f);
        }
    }
    // combine half-waves; lanes 0..31 write the fp16 row
    unsigned short hs[8];
#pragma unroll
    for (int i = 0; i < 8; ++i) {
        float tot = acc[i] + __shfl_down(acc[i], 32, 64);
        hs[i] = __half_as_ushort(__float2half_rn(tot));
    }
    if (hw == 0) {
        int4 pk;
        pk.x = (int)(hs[0] | ((unsigned)hs[1] << 16));
        pk.y = (int)(hs[2] | ((unsigned)hs[3] << 16));
        pk.z = (int)(hs[4] | ((unsigned)hs[5] << 16));
        pk.w = (int)(hs[6] | ((unsigned)hs[7] << 16));
        *reinterpret_cast<int4*>(Hagg + (size_t)node * HID + ch) = pk;
    }
}

// ------------------------------- readout -----------------------------------

__global__ __launch_bounds__(256) void readout_dot_kernel(
    const __half* __restrict__ h2, const float* __restrict__ w3,
    float* __restrict__ accum, int n) {
    const int wave = threadIdx.x >> 6;
    const int lane = threadIdx.x & 63;
    const int nwaves = gridDim.x * 4;
    const int wid = blockIdx.x * 4 + wave;
    const float2 w = *reinterpret_cast<const float2*>(w3 + lane * 2);
    float local = 0.f;
    for (int node = wid; node < n; node += nwaves) {
        __half2 v = *reinterpret_cast<const __half2*>(h2 + (size_t)node * 128 + lane * 2);
        float2 vf = __half22float2(v);
        local = fmaf(vf.x, w.x, local);
        local = fmaf(vf.y, w.y, local);
    }
    for (int off = 32; off > 0; off >>= 1) local += __shfl_down(local, off, 64);
    if (lane == 0) atomicAdd(accum, local);
}

__global__ void finalize_kernel(const float* __restrict__ accum, const float* __restrict__ b3,
                                float* __restrict__ out, float inv_n) {
    out[0] = accum[0] * inv_n + b3[0];
}

// ------------------------------- driver ------------------------------------

extern "C" void kernel_launch(void* const* d_in, const int* in_sizes, int n_in,
                              void* d_out, int out_size, void* d_ws, size_t ws_size,
                              hipStream_t stream) {
    const float* atom   = (const float*)d_in[0];
    const int*   eidx   = (const int*)d_in[1];
    const float* ef     = (const float*)d_in[2];
    const float* emb_w  = (const float*)d_in[3];
    const float* emb_b  = (const float*)d_in[4];
    const float* msg_w1 = (const float*)d_in[5];
    const float* msg_b1 = (const float*)d_in[6];
    const float* msg_w2 = (const float*)d_in[7];
    const float* msg_b2 = (const float*)d_in[8];
    const float* upd_w1 = (const float*)d_in[9];
    const float* upd_b1 = (const float*)d_in[10];
    const float* upd_w2 = (const float*)d_in[11];
    const float* upd_b2 = (const float*)d_in[12];
    const float* r_w1   = (const float*)d_in[13];
    const float* r_b1   = (const float*)d_in[14];
    const float* r_w2   = (const float*)d_in[15];
    const float* r_b2   = (const float*)d_in[16];
    const float* r_w3   = (const float*)d_in[17];
    const float* r_b3   = (const float*)d_in[18];

    const int N = in_sizes[0] / 62;
    const int E = in_sizes[1] / 2;
    const int L = in_sizes[5] / (518 * 256);
    const int* src = eidx;
    const int* dst = eidx + E;

    char* wp = (char*)d_ws;
    auto alloc = [&](size_t bytes) -> void* {
        void* p = (void*)wp;
        wp += (bytes + 255) & ~(size_t)255;
        return p;
    };
    int*   deg     = (int*)alloc((size_t)N * 4);
    int*   cursor  = (int*)alloc((size_t)N * 4);
    float* accum   = (float*)alloc(256);
    size_t zero_bytes = (size_t)((char*)accum - (char*)d_ws) + 256;
    float* degf    = (float*)alloc((size_t)N * 4);
    int*   offs    = (int*)alloc((size_t)(N + 1) * 4);
    int*   csr_src = (int*)alloc((size_t)E * 4);
    __half* ef8    = (__half*)alloc((size_t)E * 8 * 2);

    const int EMB_P = 256 * 64, PQ_P = 512 * 256, SQ_P = 256 * 256, R2_P = 128 * 256;
    // direct-use planes
    unsigned short* w_emb = (unsigned short*)alloc((size_t)EMB_P * 2 * 2);
    unsigned short* w_xu0 = (unsigned short*)alloc((size_t)SQ_P * 2 * 2);
    unsigned short* w_r2  = (unsigned short*)alloc((size_t)R2_P * 2 * 2);
    unsigned short* wF    = (unsigned short*)alloc((size_t)SQ_P * 2 * 2);
    unsigned short *wPQ[6], *wM2_[6], *wM3_[6];
    for (int l = 0; l < L; ++l) {
        wPQ[l]  = (unsigned short*)alloc((size_t)PQ_P * 2 * 2);
        wM2_[l] = (unsigned short*)alloc((size_t)SQ_P * 2 * 2);
        wM3_[l] = (unsigned short*)alloc((size_t)SQ_P * 2 * 2);
    }
    // fold B-operand planes (raw weights, converted)
    unsigned short* fb[22];
    for (int i = 0; i < 22; ++i)
        fb[i] = (unsigned short*)alloc((size_t)SQ_P * 2 * 2);
    // fold outputs fp32
    float* pscr = (float*)alloc((size_t)22 * 65536 * 4);
    float* bvec = (float*)alloc((size_t)19 * 256 * 4);

    __half* bufX0 = (__half*)alloc((size_t)N * HID * 2);
    __half* bufX1 = (__half*)alloc((size_t)N * HID * 2);
    __half* PQh   = (__half*)alloc((size_t)N * 512 * 2);
    __half* Hagg  = (__half*)alloc((size_t)N * HID * 2);  // also h2 [N,128]

    hipMemsetAsync(d_ws, 0, zero_bytes, stream);

    // ---- CSR build ----
    hist_kernel<<<(E + 255) / 256, 256, 0, stream>>>(dst, deg, E);
    scan_kernel<<<1, 256, 0, stream>>>(deg, offs, degf, N);
    scatter_kernel<<<(E + 255) / 256, 256, 0, stream>>>(src, dst, offs, cursor,
                                                        csr_src, ef, ef8, E);

    // ---- convert pass 1: direct-use weights + fold B-operands ----
    // fb slots: 0..4 W1a_l(l=1..5), 5..9 W1b_l(l=1..5), 10..14 U1a_l(l=1..5),
    //           15..20 U1b_l(l=0..5), 21 r_w1
    CTab ct1;
    int nd = 0, tiles = 0;
    auto addDesc = [&](CTab& ct, const float* s, unsigned short* dh, unsigned short* dl,
                       int Kreal, int Kpad, int srcN) {
        ct.d[nd] = {s, dh, dl, Kreal, Kpad, srcN, tiles};
        tiles += (Kpad / 32) * (srcN / 64);
        ++nd;
    };
    addDesc(ct1, emb_w, w_emb, w_emb + EMB_P, 62, 64, 256);
    addDesc(ct1, msg_w1, wPQ[0], wPQ[0] + PQ_P, 256, 256, 256);
    addDesc(ct1, msg_w1 + 256 * 256, wPQ[0] + SQ_P, wPQ[0] + PQ_P + SQ_P, 256, 256, 256);
    addDesc(ct1, upd_w1, w_xu0, w_xu0 + SQ_P, 256, 256, 256);
    addDesc(ct1, r_w2, w_r2, w_r2 + R2_P, 256, 256, 128);
    for (int l = 1; l < L; ++l) {
        addDesc(ct1, msg_w1 + (size_t)l * 518 * 256,             fb[l - 1],  fb[l - 1] + SQ_P, 256, 256, 256);
        addDesc(ct1, msg_w1 + (size_t)l * 518 * 256 + 256 * 256, fb[4 + l],  fb[4 + l] + SQ_P, 256, 256, 256);
        addDesc(ct1, upd_w1 + (size_t)l * 512 * 256,             fb[9 + l],  fb[9 + l] + SQ_P, 256, 256, 256);
    }
    for (int l = 0; l < L; ++l)
        addDesc(ct1, upd_w1 + (size_t)l * 512 * 256 + 256 * 256, fb[15 + l], fb[15 + l] + SQ_P, 256, 256, 256);
    addDesc(ct1, r_w1, fb[21], fb[21] + SQ_P, 256, 256, 256);
    ct1.nd = nd;
    convert_weights<<<tiles, 256, 0, stream>>>(ct1);

    // ---- fold GEMMs on matrix cores (one batched launch) ----
    FTab ft;
    for (int l = 1; l < L; ++l) {
        const float* U2p = upd_w2 + (size_t)(l - 1) * SQ_P;
        ft.d[l - 1] = {U2p, fb[l - 1], fb[l - 1] + SQ_P, pscr + (size_t)(l - 1) * 65536};
        ft.d[4 + l] = {U2p, fb[4 + l], fb[4 + l] + SQ_P, pscr + (size_t)(4 + l) * 65536};
        ft.d[9 + l] = {U2p, fb[9 + l], fb[9 + l] + SQ_P, pscr + (size_t)(9 + l) * 65536};
    }
    for (int l = 0; l < L; ++l)
        ft.d[15 + l] = {msg_w2 + (size_t)l * SQ_P, fb[15 + l], fb[15 + l] + SQ_P,
                        pscr + (size_t)(15 + l) * 65536};
    ft.d[21] = {upd_w2 + (size_t)5 * SQ_P, fb[21], fb[21] + SQ_P, pscr + (size_t)21 * 65536};
    fold_gemm<<<22 * 16, 256, 0, stream>>>(ft);

    // ---- convert pass 2: folded products ----
    CTab ct2;
    nd = 0; tiles = 0;
    for (int l = 1; l < L; ++l) {
        addDesc(ct2, pscr + (size_t)(l - 1) * 65536, wPQ[l], wPQ[l] + PQ_P, 256, 256, 256);
        addDesc(ct2, pscr + (size_t)(4 + l) * 65536, wPQ[l] + SQ_P, wPQ[l] + PQ_P + SQ_P, 256, 256, 256);
        addDesc(ct2, pscr + (size_t)(9 + l) * 65536, wM2_[l], wM2_[l] + SQ_P, 256, 256, 256);
    }
    for (int l = 0; l < L; ++l)
        addDesc(ct2, pscr + (size_t)(15 + l) * 65536, wM3_[l], wM3_[l] + SQ_P, 256, 256, 256);
    addDesc(ct2, pscr + (size_t)21 * 65536, wF, wF + SQ_P, 256, 256, 256);
    ct2.nd = nd;
    convert_weights<<<tiles, 256, 0, stream>>>(ct2);

    // ---- folded bias vectors ----
    BTab bt;
    for (int l = 0; l < L; ++l) {
        const float* ub2p = (l > 0) ? upd_b2 + (size_t)(l - 1) * 256 : nullptr;
        bt.d[l] = {bvec + (size_t)l * 256, msg_b1 + (size_t)l * 256,
                   ub2p, msg_w1 + (size_t)l * 518 * 256,
                   ub2p, msg_w1 + (size_t)l * 518 * 256 + 256 * 256};
        bt.d[6 + l] = {bvec + (size_t)(6 + l) * 256, upd_b1 + (size_t)l * 256,
                       ub2p, upd_w1 + (size_t)l * 512 * 256, nullptr, nullptr};
        bt.d[12 + l] = {bvec + (size_t)(12 + l) * 256, nullptr,
                        msg_b2 + (size_t)l * 256, upd_w1 + (size_t)l * 512 * 256 + 256 * 256,
                        nullptr, nullptr};
    }
    bt.d[18] = {bvec + (size_t)18 * 256, r_b1, upd_b2 + (size_t)5 * 256, r_w1,
                nullptr, nullptr};
    biasvec_kernel<<<19, 256, 0, stream>>>(bt);

    const int mblk = (N + 63) / 64;
    dim3 blk(256);

    // embed: x0 = atom @ emb_w + emb_b (fp16 out)
    mfma_gemm<<<dim3(mblk, 4), blk, 0, stream>>>(
        atom, 62, 0, w_emb, w_emb + EMB_P, 64,
        nullptr, 0, 0, nullptr, nullptr, 0,
        emb_b, nullptr, nullptr, nullptr, bufX0, N, HID, 0);

    __half* U_prev = bufX0;
    __half* U_next = bufX1;
    for (int l = 0; l < L; ++l) {
        const float* w1c = msg_w1 + (size_t)l * 518 * 256 + 512 * 256;
        const unsigned short* xu = (l == 0) ? w_xu0 : wM2_[l];

        mfma_gemm<<<dim3(mblk, 8), blk, 0, stream>>>(
            U_prev, HID, 1, wPQ[l], wPQ[l] + PQ_P, HID,
            nullptr, 0, 0, nullptr, nullptr, 0,
            nullptr, nullptr, nullptr, nullptr, PQh, N, 512, 0);
        aggregate_kernel<<<(N + 3) / 4, blk, 0, stream>>>(
            PQh, bvec + (size_t)l * 256, ef8, offs, csr_src, w1c, Hagg, N);
        mfma_gemm<<<dim3(mblk, 4), blk, 0, stream>>>(
            U_prev, HID, 1, xu, xu + SQ_P, HID,
            Hagg, HID, 1, wM3_[l], wM3_[l] + SQ_P, HID,
            bvec + (size_t)(6 + l) * 256, bvec + (size_t)(12 + l) * 256, degf,
            nullptr, U_next, N, HID, 1);
        __half* t = U_prev; U_prev = U_next; U_next = t;
    }

    // readout
    mfma_gemm<<<dim3(mblk, 4), blk, 0, stream>>>(
        U_prev, HID, 1, wF, wF + SQ_P, HID,
        nullptr, 0, 0, nullptr, nullptr, 0,
        bvec + (size_t)18 * 256, nullptr, nullptr, nullptr, U_next, N, HID, 1);
    mfma_gemm<<<dim3(mblk, 2), blk, 0, stream>>>(
        U_next, HID, 1, w_r2, w_r2 + R2_P, HID,
        nullptr, 0, 0, nullptr, nullptr, 0,
        r_b2, nullptr, nullptr, nullptr, Hagg, N, 128, 1);
    readout_dot_kernel<<<256, blk, 0, stream>>>(Hagg, r_w3, accum, N);
    finalize_kernel<<<1, 1, 0, stream>>>(accum, r_b3, (float*)d_out, 1.0f / (float)N);
}